// Round 2
// baseline (6898.217 us; speedup 1.0000x reference)
//
#include <hip/hip_runtime.h>
#include <hip/hip_bf16.h>

// LinODEnet forward, MI355X — dtype-adaptive version.
// - B=512 rows independent across the 128-step scan -> 256 blocks x 2 rows,
//   one kernel, no grid sync; all intermediate state in LDS (fp32, ~12.8KB).
// - Float inputs may arrive as bf16 OR f32 (harness flavor ambiguous). Detected
//   ON DEVICE via A's diagonal: A=0.5(W-W^T) has exact +0.0 diag; f32 words at
//   index 129k (=elem [k][k]) are 0 iff data is f32. Output dtype coupled to it.
// - mask dtype auto-detected (bf16 / f32 / u8 / i32) from byte patterns.
// - expm(A*dt) @ z replaced by order-8 Taylor ACTION on the vector:
//   v_k = (dt/k) * A v_{k-1}; zhat = sum v_k.  ||A dt|| <= ~0.25 -> err ~1e-11.
// - matvec: lane = kq(0..3) + 4*jloc; thread owns interleaved 4-elem k-chunks
//   (stride 16) so the 4 kq addresses land in distinct LDS banks; partial dots
//   combined with 2x shfl_xor; epilogue lambda on kq==0 lanes.

#define NBATCH 512
#define TLEN 128
#define DDIM 96
#define NDIM 128
#define NBLK 5
#define TAYLOR 8

typedef unsigned short u16;
typedef unsigned int u32;

__device__ __forceinline__ float bf2f(u16 u){ union{u32 i; float f;} v; v.i=((u32)u)<<16; return v.f; }
__device__ __forceinline__ float lo2f(u32 w){ union{u32 i; float f;} v; v.i=w<<16; return v.f; }
__device__ __forceinline__ float hi2f(u32 w){ union{u32 i; float f;} v; v.i=w&0xFFFF0000u; return v.f; }

// FM: 0 = bf16, 1 = f32
template<int FM>
__device__ __forceinline__ float ldf(const void* p, int i){
  if constexpr (FM==1) return ((const float*)p)[i];
  else return bf2f(((const u16*)p)[i]);
}

struct __align__(16) SMState {
  float e[2*NDIM];       // latent z (persists across steps)
  float V0[2*NDIM];      // Taylor ping
  float V1[2*NDIM];      // Taylor pong
  float zh[2*NDIM];      // zhat_pre accumulator / resnet trunk
  float h[2*NDIM];       // resnet hidden
  float xpre[2*DDIM];    // xhat_pre
  float u[2*2*DDIM];     // GRU input concat [xtilde | mask]
  float gi[2*3*DDIM];    // GRU input gates
  float gh[2*3*DDIM];    // GRU hidden gates
  float xpost[2*DDIM];   // xhat_post
};

// out[r][j] = sum_k W[j][k] * in[r][k] over 2 rows. S = per-thread k-count
// (K = 4*S). kq = lane&3 selects interleaved 4-float chunks (stride 16).
template<int FM, int S, int NO, class EPI>
__device__ __forceinline__ void mv(const void* __restrict__ W, const int ldw,
                                   const float* __restrict__ in,
                                   const int kq, const int j0, EPI epi)
{
  constexpr int K = 4*S;
  constexpr int NC = S/4;
  float a0[S], a1[S];
  {
    const float* p0 = in + 4*kq;
    const float* p1 = in + K + 4*kq;
#pragma unroll
    for (int ci=0; ci<NC; ci++){
      float4 v0 = *(const float4*)(p0 + 16*ci);
      float4 v1 = *(const float4*)(p1 + 16*ci);
      a0[4*ci+0]=v0.x; a0[4*ci+1]=v0.y; a0[4*ci+2]=v0.z; a0[4*ci+3]=v0.w;
      a1[4*ci+0]=v1.x; a1[4*ci+1]=v1.y; a1[4*ci+2]=v1.z; a1[4*ci+3]=v1.w;
    }
  }
  constexpr int P = (NO+63)/64;
  constexpr bool full = (NO%64==0);
#pragma unroll
  for (int p=0; p<P; p++){
    const int j = p*64 + j0;
    const bool act = full || (j < NO);
    float acc0=0.f, acc1=0.f;
    if (act){
      if constexpr (FM==1){
        const float* wr = (const float*)W + (size_t)j*ldw + 4*kq;
#pragma unroll
        for (int ci=0; ci<NC; ci++){
          const float4 w = *(const float4*)(wr + 16*ci);
          acc0=fmaf(w.x,a0[4*ci+0],acc0); acc1=fmaf(w.x,a1[4*ci+0],acc1);
          acc0=fmaf(w.y,a0[4*ci+1],acc0); acc1=fmaf(w.y,a1[4*ci+1],acc1);
          acc0=fmaf(w.z,a0[4*ci+2],acc0); acc1=fmaf(w.z,a1[4*ci+2],acc1);
          acc0=fmaf(w.w,a0[4*ci+3],acc0); acc1=fmaf(w.w,a1[4*ci+3],acc1);
        }
      } else {
        const u16* wr = (const u16*)W + (size_t)j*ldw + 4*kq;
#pragma unroll
        for (int ci=0; ci<NC; ci++){
          const uint2 w = *(const uint2*)(wr + 16*ci);
          float f;
          f=lo2f(w.x); acc0=fmaf(f,a0[4*ci+0],acc0); acc1=fmaf(f,a1[4*ci+0],acc1);
          f=hi2f(w.x); acc0=fmaf(f,a0[4*ci+1],acc0); acc1=fmaf(f,a1[4*ci+1],acc1);
          f=lo2f(w.y); acc0=fmaf(f,a0[4*ci+2],acc0); acc1=fmaf(f,a1[4*ci+2],acc1);
          f=hi2f(w.y); acc0=fmaf(f,a0[4*ci+3],acc0); acc1=fmaf(f,a1[4*ci+3],acc1);
        }
      }
    }
    acc0 += __shfl_xor(acc0,1,64); acc0 += __shfl_xor(acc0,2,64);
    acc1 += __shfl_xor(acc1,1,64); acc1 += __shfl_xor(acc1,2,64);
    if (act && kq==0) epi(j, acc0, acc1);
  }
  __syncthreads();
}

template<int FM>
__device__ __forceinline__ void run_all(
    SMState& sm, const int mode,
    const void* Tp, const void* Xp, const void* Mp, const void* Ap,
    const void* Wemb, const void* bemb, const void* Wproj, const void* bproj,
    const void* eW1, const void* eb1, const void* eW2, const void* eb2,
    const void* dW1, const void* db1, const void* dW2, const void* db2,
    const void* Wih, const void* Whh, const void* bih, const void* bhh,
    void* Out)
{
  const int tid  = threadIdx.x;
  const int lane = tid & 63;
  const int kq   = lane & 3;
  const int j0   = (tid>>6)*16 + (lane>>2);
  const int r0   = blockIdx.x * 2;
  constexpr int WSTRIDE = NDIM*NDIM;   // element stride per resnet block

  // ---- z0 = enc_resnet(embed(zeros)); embed(0) = b_emb ----
  {
    const int r = tid>>7, j = tid&127;
    sm.e[r*NDIM + j] = ldf<FM>(bemb, j);
  }
  __syncthreads();
#pragma unroll 1
  for (int ib=0; ib<NBLK; ib++){
    const void* W1 = (const char*)eW1 + (size_t)ib*WSTRIDE*(FM?4:2);
    const void* W2 = (const char*)eW2 + (size_t)ib*WSTRIDE*(FM?4:2);
    const int bo = ib*NDIM;
    mv<FM,32,128>(W1, NDIM, sm.e, kq, j0, [&](int j,float s0,float s1){
      const float b=ldf<FM>(eb1, bo+j);
      sm.h[j]=fmaxf(s0+b,0.f); sm.h[NDIM+j]=fmaxf(s1+b,0.f); });
    mv<FM,32,128>(W2, NDIM, sm.h, kq, j0, [&](int j,float s0,float s1){
      const float b=ldf<FM>(eb2, bo+j);
      sm.e[j]+=s0+b; sm.e[NDIM+j]+=s1+b; });
  }

  // ---- scan over time ----
#pragma unroll 1
  for (int t=0; t<TLEN; t++){
    float dtv = 0.f;
    if (t > 0) dtv = ldf<FM>(Tp,t) - ldf<FM>(Tp,t-1);

    {
      const int r = tid>>7, j = tid&127;
      const float z = sm.e[r*NDIM+j];
      sm.V0[r*NDIM+j] = z; sm.zh[r*NDIM+j] = z;
    }
    __syncthreads();

    // Taylor action: zh += sum_k (dt A)^k z / k!
#pragma unroll 1
    for (int k=1; k<=TAYLOR; k++){
      const float sc = dtv / (float)k;
      const float* Vin = (k&1) ? sm.V0 : sm.V1;
      float*      Vout = (k&1) ? sm.V1 : sm.V0;
      mv<FM,32,128>(Ap, NDIM, Vin, kq, j0, [&](int j,float s0,float s1){
        const float v0=s0*sc, v1=s1*sc;
        Vout[j]=v0; Vout[NDIM+j]=v1;
        sm.zh[j]+=v0; sm.zh[NDIM+j]+=v1; });
    }

    // decoder resnet
#pragma unroll 1
    for (int ib=0; ib<NBLK; ib++){
      const void* W1 = (const char*)dW1 + (size_t)ib*WSTRIDE*(FM?4:2);
      const void* W2 = (const char*)dW2 + (size_t)ib*WSTRIDE*(FM?4:2);
      const int bo = ib*NDIM;
      mv<FM,32,128>(W1, NDIM, sm.zh, kq, j0, [&](int j,float s0,float s1){
        const float b=ldf<FM>(db1, bo+j);
        sm.h[j]=fmaxf(s0+b,0.f); sm.h[NDIM+j]=fmaxf(s1+b,0.f); });
      mv<FM,32,128>(W2, NDIM, sm.h, kq, j0, [&](int j,float s0,float s1){
        const float b=ldf<FM>(db2, bo+j);
        sm.zh[j]+=s0+b; sm.zh[NDIM+j]+=s1+b; });
    }

    // xhat_pre = proj(zh)
    mv<FM,32,96>(Wproj, NDIM, sm.zh, kq, j0, [&](int j,float s0,float s1){
      const float b=ldf<FM>(bproj, j);
      sm.xpre[j]=s0+b; sm.xpre[DDIM+j]=s1+b; });

    // GRU input prep
    if (tid < 2*DDIM){
      const int r = tid/DDIM, d = tid - r*DDIM;
      const size_t idx = (size_t)(r0+r)*TLEN*DDIM + (size_t)t*DDIM + d;
      bool m;
      if      (mode==0) m = ((const u16*)Mp)[idx] != 0;
      else if (mode==1) m = ((const u32*)Mp)[idx] != 0;
      else if (mode==2) m = ((const unsigned char*)Mp)[idx] != 0;
      else              m = ((const int*)Mp)[idx] != 0;
      const float xv = ldf<FM>(Xp, (int)idx);
      const float xt = m ? xv : sm.xpre[r*DDIM+d];
      sm.u[r*2*DDIM + d]        = xt;
      sm.u[r*2*DDIM + DDIM + d] = m ? 1.f : 0.f;
    }
    __syncthreads();

    mv<FM,48,288>(Wih, 2*DDIM, sm.u, kq, j0, [&](int j,float s0,float s1){
      const float b=ldf<FM>(bih, j);
      sm.gi[j]=s0+b; sm.gi[3*DDIM+j]=s1+b; });
    mv<FM,24,288>(Whh, DDIM, sm.xpre, kq, j0, [&](int j,float s0,float s1){
      const float b=ldf<FM>(bhh, j);
      sm.gh[j]=s0+b; sm.gh[3*DDIM+j]=s1+b; });

    // GRU gates -> xhat_post; store output (dtype follows FM)
    if (tid < 2*DDIM){
      const int r = tid/DDIM, d = tid - r*DDIM;
      const int gb = r*3*DDIM;
      const float ir=sm.gi[gb+d], iz=sm.gi[gb+DDIM+d], in_=sm.gi[gb+2*DDIM+d];
      const float hr=sm.gh[gb+d], hz=sm.gh[gb+DDIM+d], hn=sm.gh[gb+2*DDIM+d];
      const float rg = 1.f/(1.f+__expf(-(ir+hr)));
      const float zg = 1.f/(1.f+__expf(-(iz+hz)));
      const float ag = in_ + rg*hn;
      const float e2 = __expf(2.f*ag);
      const float ng = 1.f - 2.f/(e2+1.f);      // tanh(ag)
      const float xp = sm.xpre[r*DDIM+d];
      const float xq = (1.f-zg)*ng + zg*xp;
      sm.xpost[r*DDIM+d] = xq;
      const size_t idx = (size_t)(r0+r)*TLEN*DDIM + (size_t)t*DDIM + d;
      if constexpr (FM==1) ((float*)Out)[idx] = xq;
      else ((__hip_bfloat16*)Out)[idx] = __float2bfloat16(xq);
    }
    __syncthreads();

    // e = embed(xhat_post)
    mv<FM,24,128>(Wemb, DDIM, sm.xpost, kq, j0, [&](int j,float s0,float s1){
      const float b=ldf<FM>(bemb, j);
      sm.e[j]=s0+b; sm.e[NDIM+j]=s1+b; });

    // encoder resnet -> next z
#pragma unroll 1
    for (int ib=0; ib<NBLK; ib++){
      const void* W1 = (const char*)eW1 + (size_t)ib*WSTRIDE*(FM?4:2);
      const void* W2 = (const char*)eW2 + (size_t)ib*WSTRIDE*(FM?4:2);
      const int bo = ib*NDIM;
      mv<FM,32,128>(W1, NDIM, sm.e, kq, j0, [&](int j,float s0,float s1){
        const float b=ldf<FM>(eb1, bo+j);
        sm.h[j]=fmaxf(s0+b,0.f); sm.h[NDIM+j]=fmaxf(s1+b,0.f); });
      mv<FM,32,128>(W2, NDIM, sm.h, kq, j0, [&](int j,float s0,float s1){
        const float b=ldf<FM>(eb2, bo+j);
        sm.e[j]+=s0+b; sm.e[NDIM+j]+=s1+b; });
    }
  }
}

__global__ __launch_bounds__(256, 1)
void linode_kernel(const void* Tp, const void* Xp, const void* Mp, const void* Ap,
                   const void* Wemb, const void* bemb, const void* Wproj, const void* bproj,
                   const void* eW1, const void* eb1, const void* eW2, const void* eb2,
                   const void* dW1, const void* db1, const void* dW2, const void* db2,
                   const void* Wih, const void* Whh, const void* bih, const void* bhh,
                   void* Out)
{
  __shared__ SMState sm;
  __shared__ int s_f[4];
  const int tid = threadIdx.x;

  // ---- dtype detection ----
  if (tid < 4) s_f[tid] = 0;
  __syncthreads();
  if (tid == 0){
    // f32 test: A diagonal elements [k][k] at f32 word 129k are exact +0.0
    int all0 = 1;
    for (int k=0; k<8; k++) all0 &= (((const u32*)Ap)[129*k] == 0u);
    s_f[3] = all0;   // 1 -> floats are f32
  }
  {
    const u32* mw = (const u32*)Mp;
    int fb=0, ff=0, fg=0;
    for (int i=tid; i<2048; i+=256){
      const u32 w = mw[i];
      if (w == 0x3F803F80u) fb = 1;                         // adjacent bf16 ones
      if ((w&0xFFFFu)==0x3F80u || (w>>16)==0x3F80u) ff = 1; // bf16 one / f32-one hi
      if (w > 1u) fg = 1;                                   // u8 multi-byte pattern
    }
    if (fb) atomicOr(&s_f[0],1);
    if (ff) atomicOr(&s_f[1],1);
    if (fg) atomicOr(&s_f[2],1);
  }
  __syncthreads();
  const int mode = s_f[0] ? 0 : (s_f[1] ? 1 : (s_f[2] ? 2 : 3)); // bf16/f32/u8/i32
  const int f32m = s_f[3];
  __syncthreads();

  if (f32m)
    run_all<1>(sm, mode, Tp, Xp, Mp, Ap, Wemb, bemb, Wproj, bproj,
               eW1, eb1, eW2, eb2, dW1, db1, dW2, db2, Wih, Whh, bih, bhh, Out);
  else
    run_all<0>(sm, mode, Tp, Xp, Mp, Ap, Wemb, bemb, Wproj, bproj,
               eW1, eb1, eW2, eb2, dW1, db1, dW2, db2, Wih, Whh, bih, bhh, Out);
}

extern "C" void kernel_launch(void* const* d_in, const int* in_sizes, int n_in,
                              void* d_out, int out_size, void* d_ws, size_t ws_size,
                              hipStream_t stream)
{
  (void)in_sizes; (void)n_in; (void)out_size; (void)d_ws; (void)ws_size;
  hipLaunchKernelGGL(linode_kernel, dim3(NBATCH/2), dim3(256), 0, stream,
                     d_in[0], d_in[1], d_in[2], d_in[3],
                     d_in[4], d_in[5], d_in[6], d_in[7],
                     d_in[8], d_in[9], d_in[10], d_in[11],
                     d_in[12], d_in[13], d_in[14], d_in[15],
                     d_in[16], d_in[17], d_in[18], d_in[19],
                     d_out);
}

// Round 3
// 5743.312 us; speedup vs baseline: 1.2011x; 1.2011x over previous
//
#include <hip/hip_runtime.h>
#include <hip/hip_bf16.h>

// LinODEnet forward, MI355X — r3: occupancy + ILP.
// - 512 blocks x 1 batch row (was 256 x 2): 2 blocks/CU -> 25% occupancy cap,
//   independent barrier domains per CU interleave latencies.
// - matvec: kq = lane&3 (4-way k split), 8-element chunks (uint4 weight loads,
//   8 bf16 each), 4 rotating accumulator chains (breaks dep chain), 2x shfl_xor.
// - A staged in LDS (padded stride 136 elems = 272B -> 8-way bank spread) since
//   the Taylor loop reads it 8x/step.
// - dtype-adaptive (bf16/f32 via A-diagonal test; mask bf16/f32/u8/i32).
// - expm action: zh = sum_k (dt A)^k z / k!, order 8.

#define NBATCH 512
#define TLEN 128
#define DDIM 96
#define NDIM 128
#define NBLK 5
#define TAYLOR 8

typedef unsigned short u16;
typedef unsigned int u32;

__device__ __forceinline__ float bf2f(u16 u){ union{u32 i; float f;} v; v.i=((u32)u)<<16; return v.f; }
__device__ __forceinline__ float lo2f(u32 w){ union{u32 i; float f;} v; v.i=w<<16; return v.f; }
__device__ __forceinline__ float hi2f(u32 w){ union{u32 i; float f;} v; v.i=w&0xFFFF0000u; return v.f; }

template<int FM>
__device__ __forceinline__ float ldf(const void* p, int i){
  if constexpr (FM==1) return ((const float*)p)[i];
  else return bf2f(((const u16*)p)[i]);
}

struct __align__(16) SMState {
  float e[NDIM];      // latent z
  float V0[NDIM];     // Taylor ping
  float V1[NDIM];     // Taylor pong
  float zh[NDIM];     // zhat / trunk
  float h[NDIM];      // resnet hidden
  float xpre[DDIM];
  float u[2*DDIM];
  float gi[3*DDIM];
  float gh[3*DDIM];
  float xpost[DDIM];
};

#define A_STRIDE_E 136              // elements (bf16): 272B row -> 8-way bank spread

// out[j] = sum_k W[j][k]*in[k]. S = floats per thread (K = 4*S), 8-elem chunks:
// thread (kq) owns elements 8*kq + 32*ci + n, ci<S/8. WL: weights from LDS Ash.
template<int FM, int S, int NO, bool WL, class EPI>
__device__ __forceinline__ void mv(const void* __restrict__ Wg, const u16* __restrict__ Wl,
                                   const int ldw, const float* __restrict__ in,
                                   const int kq, const int j0, EPI epi)
{
  constexpr int NC = S/8;
  float a[S];
  {
    const float* p = in + 8*kq;
#pragma unroll
    for (int ci=0; ci<NC; ci++){
      float4 v0 = *(const float4*)(p + 32*ci);
      float4 v1 = *(const float4*)(p + 32*ci + 4);
      a[8*ci+0]=v0.x; a[8*ci+1]=v0.y; a[8*ci+2]=v0.z; a[8*ci+3]=v0.w;
      a[8*ci+4]=v1.x; a[8*ci+5]=v1.y; a[8*ci+6]=v1.z; a[8*ci+7]=v1.w;
    }
  }
  constexpr int P = (NO+63)/64;
  constexpr bool full = (NO%64==0);
#pragma unroll
  for (int pp=0; pp<P; pp++){
    const int j = pp*64 + j0;
    const bool act = full || (j < NO);
    float ac0=0.f, ac1=0.f, ac2=0.f, ac3=0.f;
    if (act){
      if constexpr (WL){
        const char* wr = (const char*)Wl + 2*(size_t)j*A_STRIDE_E + 16*kq;
#pragma unroll
        for (int ci=0; ci<NC; ci++){
          const uint4 w = *(const uint4*)(wr + 64*ci);
          float f;
          f=lo2f(w.x); ac0=fmaf(f,a[8*ci+0],ac0);
          f=hi2f(w.x); ac1=fmaf(f,a[8*ci+1],ac1);
          f=lo2f(w.y); ac2=fmaf(f,a[8*ci+2],ac2);
          f=hi2f(w.y); ac3=fmaf(f,a[8*ci+3],ac3);
          f=lo2f(w.z); ac0=fmaf(f,a[8*ci+4],ac0);
          f=hi2f(w.z); ac1=fmaf(f,a[8*ci+5],ac1);
          f=lo2f(w.w); ac2=fmaf(f,a[8*ci+6],ac2);
          f=hi2f(w.w); ac3=fmaf(f,a[8*ci+7],ac3);
        }
      } else if constexpr (FM==1){
        const float* wr = (const float*)Wg + (size_t)j*ldw + 8*kq;
#pragma unroll
        for (int ci=0; ci<NC; ci++){
          const float4 w0 = *(const float4*)(wr + 32*ci);
          const float4 w1 = *(const float4*)(wr + 32*ci + 4);
          ac0=fmaf(w0.x,a[8*ci+0],ac0); ac1=fmaf(w0.y,a[8*ci+1],ac1);
          ac2=fmaf(w0.z,a[8*ci+2],ac2); ac3=fmaf(w0.w,a[8*ci+3],ac3);
          ac0=fmaf(w1.x,a[8*ci+4],ac0); ac1=fmaf(w1.y,a[8*ci+5],ac1);
          ac2=fmaf(w1.z,a[8*ci+6],ac2); ac3=fmaf(w1.w,a[8*ci+7],ac3);
        }
      } else {
        const u16* wr = (const u16*)Wg + (size_t)j*ldw + 8*kq;
#pragma unroll
        for (int ci=0; ci<NC; ci++){
          const uint4 w = *(const uint4*)(wr + 32*ci);
          float f;
          f=lo2f(w.x); ac0=fmaf(f,a[8*ci+0],ac0);
          f=hi2f(w.x); ac1=fmaf(f,a[8*ci+1],ac1);
          f=lo2f(w.y); ac2=fmaf(f,a[8*ci+2],ac2);
          f=hi2f(w.y); ac3=fmaf(f,a[8*ci+3],ac3);
          f=lo2f(w.z); ac0=fmaf(f,a[8*ci+4],ac0);
          f=hi2f(w.z); ac1=fmaf(f,a[8*ci+5],ac1);
          f=lo2f(w.w); ac2=fmaf(f,a[8*ci+6],ac2);
          f=hi2f(w.w); ac3=fmaf(f,a[8*ci+7],ac3);
        }
      }
    }
    float acc = (ac0+ac1)+(ac2+ac3);
    acc += __shfl_xor(acc,1,64); acc += __shfl_xor(acc,2,64);
    if (act && kq==0) epi(j, acc);
  }
  __syncthreads();
}

template<int FM>
__device__ __forceinline__ void run_all(
    SMState& sm, u16* Ash, const int mode,
    const void* Tp, const void* Xp, const void* Mp, const void* Ap,
    const void* Wemb, const void* bemb, const void* Wproj, const void* bproj,
    const void* eW1, const void* eb1, const void* eW2, const void* eb2,
    const void* dW1, const void* db1, const void* dW2, const void* db2,
    const void* Wih, const void* Whh, const void* bih, const void* bhh,
    void* Out)
{
  const int tid  = threadIdx.x;
  const int lane = tid & 63;
  const int kq   = lane & 3;
  const int j0   = (tid>>6)*16 + (lane>>2);
  const int r0   = blockIdx.x;            // one batch row per block
  constexpr int WB = NDIM*NDIM*(FM?4:2);  // resnet block weight bytes

  // ---- stage A into LDS (bf16 mode only), padded stride ----
  if constexpr (FM==0){
    const uint4* src = (const uint4*)Ap;          // 2048 uint4 (128x128 bf16)
    for (int i=tid; i<2048; i+=256){
      const int row = i>>4, c = i&15;
      *(uint4*)((char*)Ash + 2*(size_t)row*A_STRIDE_E + 16*c) = src[i];
    }
  }

  // ---- z0 = enc_resnet(embed(zeros)); embed(0)=b_emb ----
  if (tid < NDIM) sm.e[tid] = ldf<FM>(bemb, tid);
  __syncthreads();
#pragma unroll 1
  for (int ib=0; ib<NBLK; ib++){
    const void* W1 = (const char*)eW1 + (size_t)ib*WB;
    const void* W2 = (const char*)eW2 + (size_t)ib*WB;
    const int bo = ib*NDIM;
    mv<FM,32,128,false>(W1, nullptr, NDIM, sm.e, kq, j0, [&](int j,float s){
      sm.h[j]=fmaxf(s+ldf<FM>(eb1,bo+j),0.f); });
    mv<FM,32,128,false>(W2, nullptr, NDIM, sm.h, kq, j0, [&](int j,float s){
      sm.e[j]+=s+ldf<FM>(eb2,bo+j); });
  }

  // ---- scan over time ----
#pragma unroll 1
  for (int t=0; t<TLEN; t++){
    float dtv = 0.f;
    if (t > 0) dtv = ldf<FM>(Tp,t) - ldf<FM>(Tp,t-1);

    if (tid < NDIM){ const float z = sm.e[tid]; sm.V0[tid]=z; sm.zh[tid]=z; }
    __syncthreads();

    // Taylor action: zh += sum_k (dt A)^k z / k!
#pragma unroll 1
    for (int k=1; k<=TAYLOR; k++){
      const float sc = dtv / (float)k;
      const float* Vin = (k&1) ? sm.V0 : sm.V1;
      float*      Vout = (k&1) ? sm.V1 : sm.V0;
      if constexpr (FM==0){
        mv<FM,32,128,true>(nullptr, Ash, NDIM, Vin, kq, j0, [&](int j,float s){
          const float v=s*sc; Vout[j]=v; sm.zh[j]+=v; });
      } else {
        mv<FM,32,128,false>(Ap, nullptr, NDIM, Vin, kq, j0, [&](int j,float s){
          const float v=s*sc; Vout[j]=v; sm.zh[j]+=v; });
      }
    }

    // decoder resnet
#pragma unroll 1
    for (int ib=0; ib<NBLK; ib++){
      const void* W1 = (const char*)dW1 + (size_t)ib*WB;
      const void* W2 = (const char*)dW2 + (size_t)ib*WB;
      const int bo = ib*NDIM;
      mv<FM,32,128,false>(W1, nullptr, NDIM, sm.zh, kq, j0, [&](int j,float s){
        sm.h[j]=fmaxf(s+ldf<FM>(db1,bo+j),0.f); });
      mv<FM,32,128,false>(W2, nullptr, NDIM, sm.h, kq, j0, [&](int j,float s){
        sm.zh[j]+=s+ldf<FM>(db2,bo+j); });
    }

    // xhat_pre = proj(zh)
    mv<FM,32,96,false>(Wproj, nullptr, NDIM, sm.zh, kq, j0, [&](int j,float s){
      sm.xpre[j]=s+ldf<FM>(bproj,j); });

    // GRU input prep
    if (tid < DDIM){
      const int d = tid;
      const size_t idx = (size_t)r0*TLEN*DDIM + (size_t)t*DDIM + d;
      bool m;
      if      (mode==0) m = ((const u16*)Mp)[idx] != 0;
      else if (mode==1) m = ((const u32*)Mp)[idx] != 0;
      else if (mode==2) m = ((const unsigned char*)Mp)[idx] != 0;
      else              m = ((const int*)Mp)[idx] != 0;
      const float xv = ldf<FM>(Xp, (int)idx);
      sm.u[d]        = m ? xv : sm.xpre[d];
      sm.u[DDIM + d] = m ? 1.f : 0.f;
    }
    __syncthreads();

    mv<FM,48,288,false>(Wih, nullptr, 2*DDIM, sm.u, kq, j0, [&](int j,float s){
      sm.gi[j]=s+ldf<FM>(bih,j); });
    mv<FM,24,288,false>(Whh, nullptr, DDIM, sm.xpre, kq, j0, [&](int j,float s){
      sm.gh[j]=s+ldf<FM>(bhh,j); });

    // GRU gates -> xhat_post; store output
    if (tid < DDIM){
      const int d = tid;
      const float ir=sm.gi[d], iz=sm.gi[DDIM+d], in_=sm.gi[2*DDIM+d];
      const float hr=sm.gh[d], hz=sm.gh[DDIM+d], hn=sm.gh[2*DDIM+d];
      const float rg = 1.f/(1.f+__expf(-(ir+hr)));
      const float zg = 1.f/(1.f+__expf(-(iz+hz)));
      const float ag = in_ + rg*hn;
      const float e2 = __expf(2.f*ag);
      const float ng = 1.f - 2.f/(e2+1.f);   // tanh
      const float xp = sm.xpre[d];
      const float xq = (1.f-zg)*ng + zg*xp;
      sm.xpost[d] = xq;
      const size_t idx = (size_t)r0*TLEN*DDIM + (size_t)t*DDIM + d;
      if constexpr (FM==1) ((float*)Out)[idx] = xq;
      else ((__hip_bfloat16*)Out)[idx] = __float2bfloat16(xq);
    }
    __syncthreads();

    // e = embed(xhat_post)
    mv<FM,24,128,false>(Wemb, nullptr, DDIM, sm.xpost, kq, j0, [&](int j,float s){
      sm.e[j]=s+ldf<FM>(bemb,j); });

    // encoder resnet -> next z
#pragma unroll 1
    for (int ib=0; ib<NBLK; ib++){
      const void* W1 = (const char*)eW1 + (size_t)ib*WB;
      const void* W2 = (const char*)eW2 + (size_t)ib*WB;
      const int bo = ib*NDIM;
      mv<FM,32,128,false>(W1, nullptr, NDIM, sm.e, kq, j0, [&](int j,float s){
        sm.h[j]=fmaxf(s+ldf<FM>(eb1,bo+j),0.f); });
      mv<FM,32,128,false>(W2, nullptr, NDIM, sm.h, kq, j0, [&](int j,float s){
        sm.e[j]+=s+ldf<FM>(eb2,bo+j); });
    }
  }
}

__global__ __launch_bounds__(256, 2)
void linode_kernel(const void* Tp, const void* Xp, const void* Mp, const void* Ap,
                   const void* Wemb, const void* bemb, const void* Wproj, const void* bproj,
                   const void* eW1, const void* eb1, const void* eW2, const void* eb2,
                   const void* dW1, const void* db1, const void* dW2, const void* db2,
                   const void* Wih, const void* Whh, const void* bih, const void* bhh,
                   void* Out)
{
  __shared__ SMState sm;
  __shared__ __align__(16) u16 Ash[NDIM*A_STRIDE_E];
  __shared__ int s_f[4];
  const int tid = threadIdx.x;

  // ---- dtype detection ----
  if (tid < 4) s_f[tid] = 0;
  __syncthreads();
  if (tid == 0){
    int all0 = 1;   // A diag exact +0.0 iff f32 layout
    for (int k=0; k<8; k++) all0 &= (((const u32*)Ap)[129*k] == 0u);
    s_f[3] = all0;
  }
  {
    const u32* mw = (const u32*)Mp;
    int fb=0, ff=0, fg=0;
    for (int i=tid; i<2048; i+=256){
      const u32 w = mw[i];
      if (w == 0x3F803F80u) fb = 1;
      if ((w&0xFFFFu)==0x3F80u || (w>>16)==0x3F80u) ff = 1;
      if (w > 1u) fg = 1;
    }
    if (fb) atomicOr(&s_f[0],1);
    if (ff) atomicOr(&s_f[1],1);
    if (fg) atomicOr(&s_f[2],1);
  }
  __syncthreads();
  const int mode = s_f[0] ? 0 : (s_f[1] ? 1 : (s_f[2] ? 2 : 3));
  const int f32m = s_f[3];
  __syncthreads();

  if (f32m)
    run_all<1>(sm, Ash, mode, Tp, Xp, Mp, Ap, Wemb, bemb, Wproj, bproj,
               eW1, eb1, eW2, eb2, dW1, db1, dW2, db2, Wih, Whh, bih, bhh, Out);
  else
    run_all<0>(sm, Ash, mode, Tp, Xp, Mp, Ap, Wemb, bemb, Wproj, bproj,
               eW1, eb1, eW2, eb2, dW1, db1, dW2, db2, Wih, Whh, bih, bhh, Out);
}

extern "C" void kernel_launch(void* const* d_in, const int* in_sizes, int n_in,
                              void* d_out, int out_size, void* d_ws, size_t ws_size,
                              hipStream_t stream)
{
  (void)in_sizes; (void)n_in; (void)out_size; (void)d_ws; (void)ws_size;
  hipLaunchKernelGGL(linode_kernel, dim3(NBATCH), dim3(256), 0, stream,
                     d_in[0], d_in[1], d_in[2], d_in[3],
                     d_in[4], d_in[5], d_in[6], d_in[7],
                     d_in[8], d_in[9], d_in[10], d_in[11],
                     d_in[12], d_in[13], d_in[14], d_in[15],
                     d_in[16], d_in[17], d_in[18], d_in[19],
                     d_out);
}

// Round 4
// 5206.953 us; speedup vs baseline: 1.3248x; 1.1030x over previous
//
#include <hip/hip_runtime.h>
#include <hip/hip_bf16.h>

// LinODEnet forward, MI355X — r4.
// 1) expm(A*dt_t) PRECOMPUTED per t into d_ws (dt batch-shared; the Taylor
//    action was redundantly recomputed by all 512 blocks). Main kernel: 1 mv
//    instead of 8 per step. Fallback to in-kernel Taylor-8 if ws too small.
// 2) Main kernel 512 threads (8 waves), grid 512 -> 16 waves/CU; every NO<=128
//    matvec is a SINGLE pass (was 2). Serial pass-units/step: 64 -> 28.
// 3) Biases staged to LDS (removes L2 bias load from every mv epilogue's
//    critical path); X/mask prefetched into regs at step top.
// dtype-adaptive: floats bf16 or f32 (A-diagonal exact-zero test on device);
// mask bf16/f32/u8/i32 via byte-pattern scan. Output dtype follows input.

#define NBATCH 512
#define TLEN 128
#define DDIM 96
#define NDIM 128
#define NBLK 5
#define TAYLOR 8
#define A_STRIDE_E 136   // bf16 elems; 272B row -> 8-bank spread

typedef unsigned short u16;
typedef unsigned int u32;

__device__ __forceinline__ float bf2f(u16 u){ union{u32 i; float f;} v; v.i=((u32)u)<<16; return v.f; }
__device__ __forceinline__ float lo2f(u32 w){ union{u32 i; float f;} v; v.i=w<<16; return v.f; }
__device__ __forceinline__ float hi2f(u32 w){ union{u32 i; float f;} v; v.i=w&0xFFFF0000u; return v.f; }
__device__ __forceinline__ u16 f2bf(float x){ union{float f;u32 i;} v; v.f=x; u32 r=v.i+0x7FFF+((v.i>>16)&1); return (u16)(r>>16); }

template<int FM>
__device__ __forceinline__ float ldf(const void* p, int i){
  if constexpr (FM==1) return ((const float*)p)[i];
  else return bf2f(((const u16*)p)[i]);
}

// ---- bias LDS offsets (floats) ----
#define OEB1 0
#define OEB2 640
#define ODB1 1280
#define ODB2 1920
#define OBEMB 2560
#define OBPROJ 2688
#define OBIH 2784
#define OBHH 3072
#define NBIAS 3360

struct __align__(16) SMState {
  float e[NDIM];
  float V0[NDIM];
  float V1[NDIM];
  float zh[NDIM];
  float h[NDIM];
  float xpre[DDIM];
  float u[2*DDIM];
  float gi[3*DDIM];
  float gh[3*DDIM];
  float xpost[DDIM];
};

// ================= expm precompute =================
// grid 256: block = (t = bid>>1, half = bid&1 -> cols half*64..+64).
// Per-column Taylor-8 recurrence v_k = (dt/k) A v_{k-1}; E col = sum v_k.
// Thread (c2=tid&31, rh=tid>>5): cols {2c2,2c2+1}, rows [rh*16, rh*16+16).
__global__ __launch_bounds__(256, 1)
void expm_kernel(const void* Tp, const void* Ap, u16* Ews)
{
  __shared__ int sf;
  __shared__ __align__(16) u16 Ash2[NDIM*A_STRIDE_E];
  __shared__ __align__(16) float V[2][64*132];
  const int tid = threadIdx.x;
  if (tid==0){
    int all0=1;
    for (int k=0;k<8;k++) all0 &= (((const u32*)Ap)[129*k]==0u);
    sf = all0;           // 1 -> f32 inputs: E unused
  }
  __syncthreads();
  if (sf) return;

  const int t = blockIdx.x >> 1, half = blockIdx.x & 1;
  float dtv = 0.f;
  if (t>0) dtv = bf2f(((const u16*)Tp)[t]) - bf2f(((const u16*)Tp)[t-1]);
  {
    const uint4* src = (const uint4*)Ap;            // 128x128 bf16 = 2048 uint4
    for (int i=tid;i<2048;i+=256){
      const int row=i>>4, c=i&15;
      *(uint4*)((char*)Ash2 + 2*(size_t)row*A_STRIDE_E + 16*c) = src[i];
    }
  }
  const int c2 = tid & 31, rh = tid >> 5;
  const int j0r = rh*16;
  const int lc0 = 2*c2, lc1 = lc0+1;
  const int gc0 = half*64 + lc0, gc1 = gc0+1;

  float acc0[16], acc1[16];
#pragma unroll
  for (int jj=0;jj<16;jj++){
    const int kk = j0r+jj;
    const float i0 = (kk==gc0)?1.f:0.f, i1 = (kk==gc1)?1.f:0.f;
    acc0[jj]=i0; acc1[jj]=i1;
    V[0][lc0*132+kk]=i0; V[0][lc1*132+kk]=i1;
  }
  __syncthreads();
  int cur=0;
#pragma unroll 1
  for (int k=1;k<=8;k++){
    const float sc = dtv/(float)k;
    float o0[16], o1[16];
#pragma unroll
    for (int jj=0;jj<16;jj++){ o0[jj]=0.f; o1[jj]=0.f; }
#pragma unroll 1
    for (int kb=0;kb<16;kb++){
      const float4 va0 = *(const float4*)&V[cur][lc0*132+kb*8];
      const float4 vb0 = *(const float4*)&V[cur][lc0*132+kb*8+4];
      const float4 va1 = *(const float4*)&V[cur][lc1*132+kb*8];
      const float4 vb1 = *(const float4*)&V[cur][lc1*132+kb*8+4];
      const float v0[8]={va0.x,va0.y,va0.z,va0.w,vb0.x,vb0.y,vb0.z,vb0.w};
      const float v1[8]={va1.x,va1.y,va1.z,va1.w,vb1.x,vb1.y,vb1.z,vb1.w};
#pragma unroll
      for (int jj=0;jj<16;jj++){
        const int j = j0r+jj;
        const uint4 w = *(const uint4*)((const char*)Ash2 + 2*(size_t)j*A_STRIDE_E + 16*kb);
        float f;
        f=lo2f(w.x); o0[jj]=fmaf(f,v0[0],o0[jj]); o1[jj]=fmaf(f,v1[0],o1[jj]);
        f=hi2f(w.x); o0[jj]=fmaf(f,v0[1],o0[jj]); o1[jj]=fmaf(f,v1[1],o1[jj]);
        f=lo2f(w.y); o0[jj]=fmaf(f,v0[2],o0[jj]); o1[jj]=fmaf(f,v1[2],o1[jj]);
        f=hi2f(w.y); o0[jj]=fmaf(f,v0[3],o0[jj]); o1[jj]=fmaf(f,v1[3],o1[jj]);
        f=lo2f(w.z); o0[jj]=fmaf(f,v0[4],o0[jj]); o1[jj]=fmaf(f,v1[4],o1[jj]);
        f=hi2f(w.z); o0[jj]=fmaf(f,v0[5],o0[jj]); o1[jj]=fmaf(f,v1[5],o1[jj]);
        f=lo2f(w.w); o0[jj]=fmaf(f,v0[6],o0[jj]); o1[jj]=fmaf(f,v1[6],o1[jj]);
        f=hi2f(w.w); o0[jj]=fmaf(f,v0[7],o0[jj]); o1[jj]=fmaf(f,v1[7],o1[jj]);
      }
    }
    __syncthreads();   // all reads of V[cur] complete
#pragma unroll
    for (int jj=0;jj<16;jj++){
      const int j=j0r+jj;
      const float s0=o0[jj]*sc, s1=o1[jj]*sc;
      acc0[jj]+=s0; acc1[jj]+=s1;
      V[cur^1][lc0*132+j]=s0; V[cur^1][lc1*132+j]=s1;
    }
    __syncthreads();
    cur^=1;
  }
#pragma unroll
  for (int jj=0;jj<16;jj++){
    const int j=j0r+jj;
    const u32 pk = (u32)f2bf(acc0[jj]) | ((u32)f2bf(acc1[jj])<<16);
    *((u32*)(Ews + (size_t)t*NDIM*NDIM + (size_t)j*NDIM + gc0)) = pk;
  }
}

// ================= main kernel =================
// 512 threads. mv: kq=lane&3 (k-split), j0=(tid>>6)*16+(lane>>2) in 0..127 ->
// all NO<=128 outputs in ONE pass. S = per-thread k-count floats, NC=S/8
// uint4 (bf16) / 2x float4 (f32) weight chunks.
template<int FM, int S, int NO, bool WL, class EPI>
__device__ __forceinline__ void mv(const void* __restrict__ Wg, const u16* __restrict__ Wl,
                                   const int ldw, const float* __restrict__ in,
                                   const int kq, const int j0, EPI epi)
{
  constexpr int NC = S/8;
  constexpr int P = (NO+127)/128;
  constexpr bool full = (NO%128==0);
  float a[S];
  {
    const float* p = in + 8*kq;
#pragma unroll
    for (int ci=0; ci<NC; ci++){
      float4 v0 = *(const float4*)(p + 32*ci);
      float4 v1 = *(const float4*)(p + 32*ci + 4);
      a[8*ci+0]=v0.x; a[8*ci+1]=v0.y; a[8*ci+2]=v0.z; a[8*ci+3]=v0.w;
      a[8*ci+4]=v1.x; a[8*ci+5]=v1.y; a[8*ci+6]=v1.z; a[8*ci+7]=v1.w;
    }
  }
#pragma unroll
  for (int pp=0; pp<P; pp++){
    const int j = pp*128 + j0;
    const bool act = full || (j < NO);
    float ac0=0.f, ac1=0.f, ac2=0.f, ac3=0.f;
    if (act){
      if constexpr (WL){
        const char* wr = (const char*)Wl + 2*(size_t)j*A_STRIDE_E + 16*kq;
#pragma unroll
        for (int ci=0; ci<NC; ci++){
          const uint4 w = *(const uint4*)(wr + 64*ci);
          float f;
          f=lo2f(w.x); ac0=fmaf(f,a[8*ci+0],ac0);
          f=hi2f(w.x); ac1=fmaf(f,a[8*ci+1],ac1);
          f=lo2f(w.y); ac2=fmaf(f,a[8*ci+2],ac2);
          f=hi2f(w.y); ac3=fmaf(f,a[8*ci+3],ac3);
          f=lo2f(w.z); ac0=fmaf(f,a[8*ci+4],ac0);
          f=hi2f(w.z); ac1=fmaf(f,a[8*ci+5],ac1);
          f=lo2f(w.w); ac2=fmaf(f,a[8*ci+6],ac2);
          f=hi2f(w.w); ac3=fmaf(f,a[8*ci+7],ac3);
        }
      } else if constexpr (FM==1){
        const float* wr = (const float*)Wg + (size_t)j*ldw + 8*kq;
#pragma unroll
        for (int ci=0; ci<NC; ci++){
          const float4 w0 = *(const float4*)(wr + 32*ci);
          const float4 w1 = *(const float4*)(wr + 32*ci + 4);
          ac0=fmaf(w0.x,a[8*ci+0],ac0); ac1=fmaf(w0.y,a[8*ci+1],ac1);
          ac2=fmaf(w0.z,a[8*ci+2],ac2); ac3=fmaf(w0.w,a[8*ci+3],ac3);
          ac0=fmaf(w1.x,a[8*ci+4],ac0); ac1=fmaf(w1.y,a[8*ci+5],ac1);
          ac2=fmaf(w1.z,a[8*ci+6],ac2); ac3=fmaf(w1.w,a[8*ci+7],ac3);
        }
      } else {
        const u16* wr = (const u16*)Wg + (size_t)j*ldw + 8*kq;
#pragma unroll
        for (int ci=0; ci<NC; ci++){
          const uint4 w = *(const uint4*)(wr + 32*ci);
          float f;
          f=lo2f(w.x); ac0=fmaf(f,a[8*ci+0],ac0);
          f=hi2f(w.x); ac1=fmaf(f,a[8*ci+1],ac1);
          f=lo2f(w.y); ac2=fmaf(f,a[8*ci+2],ac2);
          f=hi2f(w.y); ac3=fmaf(f,a[8*ci+3],ac3);
          f=lo2f(w.z); ac0=fmaf(f,a[8*ci+4],ac0);
          f=hi2f(w.z); ac1=fmaf(f,a[8*ci+5],ac1);
          f=lo2f(w.w); ac2=fmaf(f,a[8*ci+6],ac2);
          f=hi2f(w.w); ac3=fmaf(f,a[8*ci+7],ac3);
        }
      }
    }
    float acc = (ac0+ac1)+(ac2+ac3);
    acc += __shfl_xor(acc,1,64); acc += __shfl_xor(acc,2,64);
    if (act && kq==0) epi(j, acc);
  }
  __syncthreads();
}

template<int FM>
__device__ __forceinline__ void stage_b(const void* src, float* dst, int n, int tid){
  for (int i=tid;i<n;i+=512) dst[i] = ldf<FM>(src,i);
}

template<int FM>
__device__ __forceinline__ void run_all(
    SMState& sm, float* smb, u16* Ash, const int mode, const int useE,
    const void* Tp, const void* Xp, const void* Mp, const void* Ap,
    const void* Wemb, const void* bemb, const void* Wproj, const void* bproj,
    const void* eW1, const void* eb1, const void* eW2, const void* eb2,
    const void* dW1, const void* db1, const void* dW2, const void* db2,
    const void* Wih, const void* Whh, const void* bih, const void* bhh,
    const u16* Ep, void* Out)
{
  const int tid  = threadIdx.x;
  const int lane = tid & 63;
  const int kq   = lane & 3;
  const int j0   = (tid>>6)*16 + (lane>>2);   // 0..127
  const int r0   = blockIdx.x;
  constexpr int WB = NDIM*NDIM*(FM?4:2);

  // ---- stage biases to LDS ----
  stage_b<FM>(eb1, smb+OEB1, NBLK*NDIM, tid);
  stage_b<FM>(eb2, smb+OEB2, NBLK*NDIM, tid);
  stage_b<FM>(db1, smb+ODB1, NBLK*NDIM, tid);
  stage_b<FM>(db2, smb+ODB2, NBLK*NDIM, tid);
  stage_b<FM>(bemb, smb+OBEMB, NDIM, tid);
  stage_b<FM>(bproj, smb+OBPROJ, DDIM, tid);
  stage_b<FM>(bih, smb+OBIH, 3*DDIM, tid);
  stage_b<FM>(bhh, smb+OBHH, 3*DDIM, tid);
  // ---- stage A (Taylor fallback only) ----
  if (FM==0 && !useE){
    const uint4* src = (const uint4*)Ap;
    for (int i=tid;i<2048;i+=512){
      const int row=i>>4, c=i&15;
      *(uint4*)((char*)Ash + 2*(size_t)row*A_STRIDE_E + 16*c) = src[i];
    }
  }
  __syncthreads();

  // ---- z0 = enc(embed(0)); embed(0)=b_emb ----
  if (tid < NDIM) sm.e[tid] = smb[OBEMB+tid];
  __syncthreads();
#pragma unroll 1
  for (int ib=0; ib<NBLK; ib++){
    const void* W1 = (const char*)eW1 + (size_t)ib*WB;
    const void* W2 = (const char*)eW2 + (size_t)ib*WB;
    const int bo = ib*NDIM;
    mv<FM,32,128,false>(W1, nullptr, NDIM, sm.e, kq, j0, [&](int j,float s){
      sm.h[j]=fmaxf(s+smb[OEB1+bo+j],0.f); });
    mv<FM,32,128,false>(W2, nullptr, NDIM, sm.h, kq, j0, [&](int j,float s){
      sm.e[j]+=s+smb[OEB2+bo+j]; });
  }

  // ---- scan ----
#pragma unroll 1
  for (int t=0; t<TLEN; t++){
    // prefetch X/mask for this step (consumed ~8 mvs later)
    float xv_r = 0.f; int m_r = 0;
    if (tid < DDIM){
      const size_t idx = (size_t)r0*TLEN*DDIM + (size_t)t*DDIM + tid;
      if      (mode==0) m_r = ((const u16*)Mp)[idx] != 0;
      else if (mode==1) m_r = ((const u32*)Mp)[idx] != 0;
      else if (mode==2) m_r = ((const unsigned char*)Mp)[idx] != 0;
      else              m_r = ((const int*)Mp)[idx] != 0;
      xv_r = ldf<FM>(Xp, (int)idx);
    }

    if (FM==0 && useE){
      const u16* Et = Ep + (size_t)t*NDIM*NDIM;
      mv<0,32,128,false>(Et, nullptr, NDIM, sm.e, kq, j0, [&](int j,float s){
        sm.zh[j]=s; });
    } else {
      float dtv = 0.f;
      if (t>0) dtv = ldf<FM>(Tp,t) - ldf<FM>(Tp,t-1);
      if (tid < NDIM){ const float z=sm.e[tid]; sm.V0[tid]=z; sm.zh[tid]=z; }
      __syncthreads();
#pragma unroll 1
      for (int k=1;k<=TAYLOR;k++){
        const float sc = dtv/(float)k;
        const float* Vin = (k&1)?sm.V0:sm.V1;
        float*      Vout = (k&1)?sm.V1:sm.V0;
        if constexpr (FM==0){
          mv<0,32,128,true>(nullptr, Ash, NDIM, Vin, kq, j0, [&](int j,float s){
            const float v=s*sc; Vout[j]=v; sm.zh[j]+=v; });
        } else {
          mv<1,32,128,false>(Ap, nullptr, NDIM, Vin, kq, j0, [&](int j,float s){
            const float v=s*sc; Vout[j]=v; sm.zh[j]+=v; });
        }
      }
    }

    // decoder resnet
#pragma unroll 1
    for (int ib=0; ib<NBLK; ib++){
      const void* W1 = (const char*)dW1 + (size_t)ib*WB;
      const void* W2 = (const char*)dW2 + (size_t)ib*WB;
      const int bo = ib*NDIM;
      mv<FM,32,128,false>(W1, nullptr, NDIM, sm.zh, kq, j0, [&](int j,float s){
        sm.h[j]=fmaxf(s+smb[ODB1+bo+j],0.f); });
      mv<FM,32,128,false>(W2, nullptr, NDIM, sm.h, kq, j0, [&](int j,float s){
        sm.zh[j]+=s+smb[ODB2+bo+j]; });
    }

    // xhat_pre = proj(zh)
    mv<FM,32,96,false>(Wproj, nullptr, NDIM, sm.zh, kq, j0, [&](int j,float s){
      sm.xpre[j]=s+smb[OBPROJ+j]; });

    // GRU input u = [xtilde | mask]
    if (tid < DDIM){
      sm.u[tid]      = m_r ? xv_r : sm.xpre[tid];
      sm.u[DDIM+tid] = m_r ? 1.f : 0.f;
    }
    __syncthreads();

    mv<FM,48,288,false>(Wih, nullptr, 2*DDIM, sm.u, kq, j0, [&](int j,float s){
      sm.gi[j]=s+smb[OBIH+j]; });
    mv<FM,24,288,false>(Whh, nullptr, DDIM, sm.xpre, kq, j0, [&](int j,float s){
      sm.gh[j]=s+smb[OBHH+j]; });

    // GRU gates -> xhat_post; store
    if (tid < DDIM){
      const int d = tid;
      const float ir=sm.gi[d], iz=sm.gi[DDIM+d], in_=sm.gi[2*DDIM+d];
      const float hr=sm.gh[d], hz=sm.gh[DDIM+d], hn=sm.gh[2*DDIM+d];
      const float rg = 1.f/(1.f+__expf(-(ir+hr)));
      const float zg = 1.f/(1.f+__expf(-(iz+hz)));
      const float ag = in_ + rg*hn;
      const float e2 = __expf(2.f*ag);
      const float ng = 1.f - 2.f/(e2+1.f);
      const float xp = sm.xpre[d];
      const float xq = (1.f-zg)*ng + zg*xp;
      sm.xpost[d] = xq;
      const size_t idx = (size_t)r0*TLEN*DDIM + (size_t)t*DDIM + d;
      if constexpr (FM==1) ((float*)Out)[idx] = xq;
      else ((__hip_bfloat16*)Out)[idx] = __float2bfloat16(xq);
    }
    __syncthreads();

    // e = embed(xpost)
    mv<FM,24,128,false>(Wemb, nullptr, DDIM, sm.xpost, kq, j0, [&](int j,float s){
      sm.e[j]=s+smb[OBEMB+j]; });

    // encoder resnet -> next z
#pragma unroll 1
    for (int ib=0; ib<NBLK; ib++){
      const void* W1 = (const char*)eW1 + (size_t)ib*WB;
      const void* W2 = (const char*)eW2 + (size_t)ib*WB;
      const int bo = ib*NDIM;
      mv<FM,32,128,false>(W1, nullptr, NDIM, sm.e, kq, j0, [&](int j,float s){
        sm.h[j]=fmaxf(s+smb[OEB1+bo+j],0.f); });
      mv<FM,32,128,false>(W2, nullptr, NDIM, sm.h, kq, j0, [&](int j,float s){
        sm.e[j]+=s+smb[OEB2+bo+j]; });
    }
  }
}

__global__ __launch_bounds__(512, 4)
void linode_kernel(const void* Tp, const void* Xp, const void* Mp, const void* Ap,
                   const void* Wemb, const void* bemb, const void* Wproj, const void* bproj,
                   const void* eW1, const void* eb1, const void* eW2, const void* eb2,
                   const void* dW1, const void* db1, const void* dW2, const void* db2,
                   const void* Wih, const void* Whh, const void* bih, const void* bhh,
                   const u16* Ep, const int useE, void* Out)
{
  __shared__ SMState sm;
  __shared__ float smb[NBIAS];
  __shared__ __align__(16) u16 Ash[NDIM*A_STRIDE_E];
  __shared__ int s_f[4];
  const int tid = threadIdx.x;

  if (tid < 4) s_f[tid] = 0;
  __syncthreads();
  if (tid == 0){
    int all0 = 1;
    for (int k=0;k<8;k++) all0 &= (((const u32*)Ap)[129*k] == 0u);
    s_f[3] = all0;
  }
  {
    const u32* mw = (const u32*)Mp;
    int fb=0, ff=0, fg=0;
    for (int i=tid;i<2048;i+=512){
      const u32 w = mw[i];
      if (w == 0x3F803F80u) fb = 1;
      if ((w&0xFFFFu)==0x3F80u || (w>>16)==0x3F80u) ff = 1;
      if (w > 1u) fg = 1;
    }
    if (fb) atomicOr(&s_f[0],1);
    if (ff) atomicOr(&s_f[1],1);
    if (fg) atomicOr(&s_f[2],1);
  }
  __syncthreads();
  const int mode = s_f[0] ? 0 : (s_f[1] ? 1 : (s_f[2] ? 2 : 3));
  const int f32m = s_f[3];
  __syncthreads();

  if (f32m)
    run_all<1>(sm, smb, Ash, mode, useE, Tp, Xp, Mp, Ap, Wemb, bemb, Wproj, bproj,
               eW1, eb1, eW2, eb2, dW1, db1, dW2, db2, Wih, Whh, bih, bhh, Ep, Out);
  else
    run_all<0>(sm, smb, Ash, mode, useE, Tp, Xp, Mp, Ap, Wemb, bemb, Wproj, bproj,
               eW1, eb1, eW2, eb2, dW1, db1, dW2, db2, Wih, Whh, bih, bhh, Ep, Out);
}

extern "C" void kernel_launch(void* const* d_in, const int* in_sizes, int n_in,
                              void* d_out, int out_size, void* d_ws, size_t ws_size,
                              hipStream_t stream)
{
  (void)in_sizes; (void)n_in; (void)out_size;
  const int useE = (ws_size >= (size_t)TLEN*NDIM*NDIM*2) ? 1 : 0;
  if (useE)
    hipLaunchKernelGGL(expm_kernel, dim3(2*TLEN), dim3(256), 0, stream,
                       d_in[0], d_in[3], (u16*)d_ws);
  hipLaunchKernelGGL(linode_kernel, dim3(NBATCH), dim3(512), 0, stream,
                     d_in[0], d_in[1], d_in[2], d_in[3],
                     d_in[4], d_in[5], d_in[6], d_in[7],
                     d_in[8], d_in[9], d_in[10], d_in[11],
                     d_in[12], d_in[13], d_in[14], d_in[15],
                     d_in[16], d_in[17], d_in[18], d_in[19],
                     (const u16*)d_ws, useE, d_out);
}

// Round 5
// 5194.094 us; speedup vs baseline: 1.3281x; 1.0025x over previous
//
#include <hip/hip_runtime.h>
#include <hip/hip_bf16.h>

// LinODEnet forward, MI355X — r5: cross-barrier weight prefetch.
// r4 post-mortem: 42% occupancy but VALUBusy 27% -> each of ~3300 serial
// matvec stages exposed full L2 weight-load latency because loads sit after
// the preceding __syncthreads (compiler can't hoist across s_barrier).
// r5: stage n issues stage n+1's pass-0 weight loads into uint4 wp[6]
// BEFORE the barrier -> latency hidden under reduce/epilogue/barrier/act-read.
// Also fuses the GRU u-write into the proj epilogue (one fewer barrier/step).
// Keeps: expm(A*dt) precompute into d_ws (batch-shared), 512 thr/block,
// 1 row/block, biases in LDS, dtype auto-detect with Taylor/f32 fallback.

#define NBATCH 512
#define TLEN 128
#define DDIM 96
#define NDIM 128
#define NBLK 5
#define TAYLOR 8
#define A_STRIDE_E 136   // bf16 elems; 272B row

typedef unsigned short u16;
typedef unsigned int u32;

__device__ __forceinline__ float bf2f(u16 u){ union{u32 i; float f;} v; v.i=((u32)u)<<16; return v.f; }
__device__ __forceinline__ float lo2f(u32 w){ union{u32 i; float f;} v; v.i=w<<16; return v.f; }
__device__ __forceinline__ float hi2f(u32 w){ union{u32 i; float f;} v; v.i=w&0xFFFF0000u; return v.f; }
__device__ __forceinline__ u16 f2bf(float x){ union{float f;u32 i;} v; v.f=x; u32 r=v.i+0x7FFF+((v.i>>16)&1); return (u16)(r>>16); }

template<int FM>
__device__ __forceinline__ float ldf(const void* p, int i){
  if constexpr (FM==1) return ((const float*)p)[i];
  else return bf2f(((const u16*)p)[i]);
}

// bias LDS offsets (floats)
#define OEB1 0
#define OEB2 640
#define ODB1 1280
#define ODB2 1920
#define OBEMB 2560
#define OBPROJ 2688
#define OBIH 2784
#define OBHH 3072
#define NBIAS 3360

struct __align__(16) SMState {
  float e[NDIM];
  float V0[NDIM];
  float V1[NDIM];
  float zh[NDIM];
  float h[NDIM];
  float xpre[DDIM];
  float u[2*DDIM];
  float gi[3*DDIM];
  float gh[3*DDIM];
  float xpost[DDIM];
};

// ================= expm precompute (unchanged from r4) =================
__global__ __launch_bounds__(256, 1)
void expm_kernel(const void* Tp, const void* Ap, u16* Ews)
{
  __shared__ int sf;
  __shared__ __align__(16) u16 Ash2[NDIM*A_STRIDE_E];
  __shared__ __align__(16) float V[2][64*132];
  const int tid = threadIdx.x;
  if (tid==0){
    int all0=1;
    for (int k=0;k<8;k++) all0 &= (((const u32*)Ap)[129*k]==0u);
    sf = all0;
  }
  __syncthreads();
  if (sf) return;

  const int t = blockIdx.x >> 1, half = blockIdx.x & 1;
  float dtv = 0.f;
  if (t>0) dtv = bf2f(((const u16*)Tp)[t]) - bf2f(((const u16*)Tp)[t-1]);
  {
    const uint4* src = (const uint4*)Ap;
    for (int i=tid;i<2048;i+=256){
      const int row=i>>4, c=i&15;
      *(uint4*)((char*)Ash2 + 2*(size_t)row*A_STRIDE_E + 16*c) = src[i];
    }
  }
  const int c2 = tid & 31, rh = tid >> 5;
  const int j0r = rh*16;
  const int lc0 = 2*c2, lc1 = lc0+1;
  const int gc0 = half*64 + lc0, gc1 = gc0+1;

  float acc0[16], acc1[16];
#pragma unroll
  for (int jj=0;jj<16;jj++){
    const int kk = j0r+jj;
    const float i0 = (kk==gc0)?1.f:0.f, i1 = (kk==gc1)?1.f:0.f;
    acc0[jj]=i0; acc1[jj]=i1;
    V[0][lc0*132+kk]=i0; V[0][lc1*132+kk]=i1;
  }
  __syncthreads();
  int cur=0;
#pragma unroll 1
  for (int k=1;k<=8;k++){
    const float sc = dtv/(float)k;
    float o0[16], o1[16];
#pragma unroll
    for (int jj=0;jj<16;jj++){ o0[jj]=0.f; o1[jj]=0.f; }
#pragma unroll 1
    for (int kb=0;kb<16;kb++){
      const float4 va0 = *(const float4*)&V[cur][lc0*132+kb*8];
      const float4 vb0 = *(const float4*)&V[cur][lc0*132+kb*8+4];
      const float4 va1 = *(const float4*)&V[cur][lc1*132+kb*8];
      const float4 vb1 = *(const float4*)&V[cur][lc1*132+kb*8+4];
      const float v0[8]={va0.x,va0.y,va0.z,va0.w,vb0.x,vb0.y,vb0.z,vb0.w};
      const float v1[8]={va1.x,va1.y,va1.z,va1.w,vb1.x,vb1.y,vb1.z,vb1.w};
#pragma unroll
      for (int jj=0;jj<16;jj++){
        const int j = j0r+jj;
        const uint4 w = *(const uint4*)((const char*)Ash2 + 2*(size_t)j*A_STRIDE_E + 16*kb);
        float f;
        f=lo2f(w.x); o0[jj]=fmaf(f,v0[0],o0[jj]); o1[jj]=fmaf(f,v1[0],o1[jj]);
        f=hi2f(w.x); o0[jj]=fmaf(f,v0[1],o0[jj]); o1[jj]=fmaf(f,v1[1],o1[jj]);
        f=lo2f(w.y); o0[jj]=fmaf(f,v0[2],o0[jj]); o1[jj]=fmaf(f,v1[2],o1[jj]);
        f=hi2f(w.y); o0[jj]=fmaf(f,v0[3],o0[jj]); o1[jj]=fmaf(f,v1[3],o1[jj]);
        f=lo2f(w.z); o0[jj]=fmaf(f,v0[4],o0[jj]); o1[jj]=fmaf(f,v1[4],o1[jj]);
        f=hi2f(w.z); o0[jj]=fmaf(f,v0[5],o0[jj]); o1[jj]=fmaf(f,v1[5],o1[jj]);
        f=lo2f(w.w); o0[jj]=fmaf(f,v0[6],o0[jj]); o1[jj]=fmaf(f,v1[6],o1[jj]);
        f=hi2f(w.w); o0[jj]=fmaf(f,v0[7],o0[jj]); o1[jj]=fmaf(f,v1[7],o1[jj]);
      }
    }
    __syncthreads();
#pragma unroll
    for (int jj=0;jj<16;jj++){
      const int j=j0r+jj;
      const float s0=o0[jj]*sc, s1=o1[jj]*sc;
      acc0[jj]+=s0; acc1[jj]+=s1;
      V[cur^1][lc0*132+j]=s0; V[cur^1][lc1*132+j]=s1;
    }
    __syncthreads();
    cur^=1;
  }
#pragma unroll
  for (int jj=0;jj<16;jj++){
    const int j=j0r+jj;
    const u32 pk = (u32)f2bf(acc0[jj]) | ((u32)f2bf(acc1[jj])<<16);
    *((u32*)(Ews + (size_t)t*NDIM*NDIM + (size_t)j*NDIM + gc0)) = pk;
  }
}

// ================= pipelined bf16 helpers =================
template<int NC>
__device__ __forceinline__ void wload(uint4* wp, const u16* W, int ldw_e, int j, int kq){
  const u16* wr = W + (size_t)j*ldw_e + 8*kq;
#pragma unroll
  for (int ci=0; ci<NC; ci++) wp[ci] = *(const uint4*)(wr + 32*ci);
}
template<int S>
__device__ __forceinline__ void aload(float* a, const float* in, int kq){
  const float* p = in + 8*kq;
#pragma unroll
  for (int ci=0; ci<S/8; ci++){
    float4 v0 = *(const float4*)(p + 32*ci);
    float4 v1 = *(const float4*)(p + 32*ci + 4);
    a[8*ci+0]=v0.x; a[8*ci+1]=v0.y; a[8*ci+2]=v0.z; a[8*ci+3]=v0.w;
    a[8*ci+4]=v1.x; a[8*ci+5]=v1.y; a[8*ci+6]=v1.z; a[8*ci+7]=v1.w;
  }
}
template<int NC>
__device__ __forceinline__ float dotw(const uint4* wp, const float* a){
  float ac0=0.f,ac1=0.f,ac2=0.f,ac3=0.f;
#pragma unroll
  for (int ci=0; ci<NC; ci++){
    const uint4 w = wp[ci]; float f;
    f=lo2f(w.x); ac0=fmaf(f,a[8*ci+0],ac0);
    f=hi2f(w.x); ac1=fmaf(f,a[8*ci+1],ac1);
    f=lo2f(w.y); ac2=fmaf(f,a[8*ci+2],ac2);
    f=hi2f(w.y); ac3=fmaf(f,a[8*ci+3],ac3);
    f=lo2f(w.z); ac0=fmaf(f,a[8*ci+4],ac0);
    f=hi2f(w.z); ac1=fmaf(f,a[8*ci+5],ac1);
    f=lo2f(w.w); ac2=fmaf(f,a[8*ci+6],ac2);
    f=hi2f(w.w); ac3=fmaf(f,a[8*ci+7],ac3);
  }
  return (ac0+ac1)+(ac2+ac3);
}
template<int NC>
__device__ __forceinline__ float dotl(const u16* W, int ldw_e, int j, int kq, const float* a){
  uint4 wl[NC]; wload<NC>(wl,W,ldw_e,j,kq); return dotw<NC>(wl,a);
}
__device__ __forceinline__ float red4(float x){
  x += __shfl_xor(x,1,64); x += __shfl_xor(x,2,64); return x;
}

// ================= pipelined main path (bf16 + precomputed E) =================
__device__ __forceinline__ void run_pipe(
    SMState& sm, float* smb, const int mode,
    const void* Xp, const void* Mp,
    const u16* Wemb, const u16* Wproj,
    const u16* eW1, const u16* eW2,
    const u16* dW1, const u16* dW2,
    const u16* Wih, const u16* Whh,
    const u16* Ep, __hip_bfloat16* Out)
{
  const int tid  = threadIdx.x;
  const int lane = tid & 63;
  const int kq   = lane & 3;
  const int j0   = (tid>>6)*16 + (lane>>2);   // 0..127
  const int r0   = blockIdx.x;
  const bool epl = (kq==0);

  // ---- z0 = enc(embed(0)); embed(0)=b_emb (runs once; inline loads) ----
  if (tid < NDIM) sm.e[tid] = smb[OBEMB+tid];
  __syncthreads();
  {
    float a[32];
#pragma unroll 1
    for (int ib=0; ib<NBLK; ib++){
      aload<32>(a, sm.e, kq);
      float acc = red4(dotl<4>(eW1+ib*NDIM*NDIM, NDIM, j0, kq, a));
      if (epl) sm.h[j0]=fmaxf(acc+smb[OEB1+ib*NDIM+j0],0.f);
      __syncthreads();
      aload<32>(a, sm.h, kq);
      acc = red4(dotl<4>(eW2+ib*NDIM*NDIM, NDIM, j0, kq, a));
      if (epl) sm.e[j0]+=acc+smb[OEB2+ib*NDIM+j0];
      __syncthreads();
    }
  }

  uint4 wp[6];                      // pipelined weight buffer (pass-0 of next stage)
  wload<4>(wp, Ep, NDIM, j0, kq);   // prime with E_0

#pragma unroll 1
  for (int t=0; t<TLEN; t++){
    // X/mask prefetch on the epilogue lanes (d = j0)
    float xv_r = 0.f; int m_r = 0;
    if (epl && j0 < DDIM){
      const size_t idx = (size_t)r0*TLEN*DDIM + (size_t)t*DDIM + j0;
      if      (mode==0) m_r = ((const u16*)Mp)[idx] != 0;
      else if (mode==1) m_r = ((const u32*)Mp)[idx] != 0;
      else if (mode==2) m_r = ((const unsigned char*)Mp)[idx] != 0;
      else              m_r = ((const int*)Mp)[idx] != 0;
      xv_r = bf2f(((const u16*)Xp)[idx]);
    }

    // S0: zh = E_t e
    {
      float a[32]; aload<32>(a, sm.e, kq);
      float acc = dotw<4>(wp, a);
      wload<4>(wp, dW1, NDIM, j0, kq);                   // prefetch dec W1(0)
      acc = red4(acc);
      if (epl) sm.zh[j0] = acc;
    }
    __syncthreads();

    // decoder resnet
#pragma unroll 1
    for (int ib=0; ib<NBLK; ib++){
      float a[32];
      aload<32>(a, sm.zh, kq);
      float acc = dotw<4>(wp, a);
      wload<4>(wp, dW2+ib*NDIM*NDIM, NDIM, j0, kq);      // prefetch dec W2(ib)
      acc = red4(acc);
      if (epl) sm.h[j0]=fmaxf(acc+smb[ODB1+ib*NDIM+j0],0.f);
      __syncthreads();
      aload<32>(a, sm.h, kq);
      acc = dotw<4>(wp, a);
      if (ib<NBLK-1) wload<4>(wp, dW1+(ib+1)*NDIM*NDIM, NDIM, j0, kq);
      else           wload<4>(wp, Wproj, NDIM, (j0<DDIM?j0:DDIM-1), kq);
      acc = red4(acc);
      if (epl) sm.zh[j0]+=acc+smb[ODB2+ib*NDIM+j0];
      __syncthreads();
    }

    // proj + fused GRU-input write
    {
      float a[32]; aload<32>(a, sm.zh, kq);
      float acc = dotw<4>(wp, a);
      wload<6>(wp, Wih, 2*DDIM, j0, kq);                 // prefetch gi pass0
      acc = red4(acc);
      if (epl && j0 < DDIM){
        const float xp = acc + smb[OBPROJ+j0];
        sm.xpre[j0] = xp;
        sm.u[j0]      = m_r ? xv_r : xp;
        sm.u[DDIM+j0] = m_r ? 1.f : 0.f;
      }
    }
    __syncthreads();

    // gi = u @ Wih^T + bih  (288 outputs, 3 passes)
    {
      float a[48]; aload<48>(a, sm.u, kq);
      float g0 = dotw<6>(wp, a);
      wload<3>(wp, Whh, DDIM, j0, kq);                   // prefetch gh pass0
      float g1 = dotl<6>(Wih, 2*DDIM, 128+j0, kq, a);
      float g2 = (j0<32) ? dotl<6>(Wih, 2*DDIM, 256+j0, kq, a) : 0.f;
      g0=red4(g0); g1=red4(g1); g2=red4(g2);
      if (epl){
        sm.gi[j0]     = g0 + smb[OBIH+j0];
        sm.gi[128+j0] = g1 + smb[OBIH+128+j0];
        if (j0<32) sm.gi[256+j0] = g2 + smb[OBIH+256+j0];
      }
    }
    __syncthreads();

    // gh = xpre @ Whh^T + bhh  (288 outputs, 3 passes)
    {
      float a[24]; aload<24>(a, sm.xpre, kq);
      float g0 = dotw<3>(wp, a);
      wload<3>(wp, Wemb, DDIM, j0, kq);                  // prefetch emb
      float g1 = dotl<3>(Whh, DDIM, 128+j0, kq, a);
      float g2 = (j0<32) ? dotl<3>(Whh, DDIM, 256+j0, kq, a) : 0.f;
      g0=red4(g0); g1=red4(g1); g2=red4(g2);
      if (epl){
        sm.gh[j0]     = g0 + smb[OBHH+j0];
        sm.gh[128+j0] = g1 + smb[OBHH+128+j0];
        if (j0<32) sm.gh[256+j0] = g2 + smb[OBHH+256+j0];
      }
    }
    __syncthreads();

    // GRU gates -> xhat_post; store output
    if (tid < DDIM){
      const int d = tid;
      const float ir=sm.gi[d], iz=sm.gi[DDIM+d], in_=sm.gi[2*DDIM+d];
      const float hr=sm.gh[d], hz=sm.gh[DDIM+d], hn=sm.gh[2*DDIM+d];
      const float rg = 1.f/(1.f+__expf(-(ir+hr)));
      const float zg = 1.f/(1.f+__expf(-(iz+hz)));
      const float ag = in_ + rg*hn;
      const float e2 = __expf(2.f*ag);
      const float ng = 1.f - 2.f/(e2+1.f);
      const float xp = sm.xpre[d];
      const float xq = (1.f-zg)*ng + zg*xp;
      sm.xpost[d] = xq;
      const size_t idx = (size_t)r0*TLEN*DDIM + (size_t)t*DDIM + d;
      Out[idx] = __float2bfloat16(xq);
    }
    __syncthreads();

    // e = embed(xpost)
    {
      float a[24]; aload<24>(a, sm.xpost, kq);
      float acc = dotw<3>(wp, a);
      wload<4>(wp, eW1, NDIM, j0, kq);                   // prefetch enc W1(0)
      acc = red4(acc);
      if (epl) sm.e[j0] = acc + smb[OBEMB+j0];
    }
    __syncthreads();

    // encoder resnet -> next z
#pragma unroll 1
    for (int ib=0; ib<NBLK; ib++){
      float a[32];
      aload<32>(a, sm.e, kq);
      float acc = dotw<4>(wp, a);
      wload<4>(wp, eW2+ib*NDIM*NDIM, NDIM, j0, kq);      // prefetch enc W2(ib)
      acc = red4(acc);
      if (epl) sm.h[j0]=fmaxf(acc+smb[OEB1+ib*NDIM+j0],0.f);
      __syncthreads();
      aload<32>(a, sm.h, kq);
      acc = dotw<4>(wp, a);
      if (ib<NBLK-1) wload<4>(wp, eW1+(ib+1)*NDIM*NDIM, NDIM, j0, kq);
      else {
        const u16* En = Ep + (size_t)((t+1<TLEN)?(t+1):t)*NDIM*NDIM;
        wload<4>(wp, En, NDIM, j0, kq);                  // prefetch E_{t+1}
      }
      acc = red4(acc);
      if (epl) sm.e[j0]+=acc+smb[OEB2+ib*NDIM+j0];
      __syncthreads();
    }
  }
}

// ================= fallback matvec (f32 inputs or no workspace) =================
template<int FM, int S, int NO, bool WL, class EPI>
__device__ __forceinline__ void mv(const void* __restrict__ Wg, const u16* __restrict__ Wl,
                                   const int ldw, const float* __restrict__ in,
                                   const int kq, const int j0, EPI epi)
{
  constexpr int NC = S/8;
  constexpr int P = (NO+127)/128;
  constexpr bool full = (NO%128==0);
  float a[S];
  {
    const float* p = in + 8*kq;
#pragma unroll
    for (int ci=0; ci<NC; ci++){
      float4 v0 = *(const float4*)(p + 32*ci);
      float4 v1 = *(const float4*)(p + 32*ci + 4);
      a[8*ci+0]=v0.x; a[8*ci+1]=v0.y; a[8*ci+2]=v0.z; a[8*ci+3]=v0.w;
      a[8*ci+4]=v1.x; a[8*ci+5]=v1.y; a[8*ci+6]=v1.z; a[8*ci+7]=v1.w;
    }
  }
#pragma unroll
  for (int pp=0; pp<P; pp++){
    const int j = pp*128 + j0;
    const bool act = full || (j < NO);
    float ac0=0.f, ac1=0.f, ac2=0.f, ac3=0.f;
    if (act){
      if constexpr (WL){
        const char* wr = (const char*)Wl + 2*(size_t)j*A_STRIDE_E + 16*kq;
#pragma unroll
        for (int ci=0; ci<NC; ci++){
          const uint4 w = *(const uint4*)(wr + 64*ci);
          float f;
          f=lo2f(w.x); ac0=fmaf(f,a[8*ci+0],ac0);
          f=hi2f(w.x); ac1=fmaf(f,a[8*ci+1],ac1);
          f=lo2f(w.y); ac2=fmaf(f,a[8*ci+2],ac2);
          f=hi2f(w.y); ac3=fmaf(f,a[8*ci+3],ac3);
          f=lo2f(w.z); ac0=fmaf(f,a[8*ci+4],ac0);
          f=hi2f(w.z); ac1=fmaf(f,a[8*ci+5],ac1);
          f=lo2f(w.w); ac2=fmaf(f,a[8*ci+6],ac2);
          f=hi2f(w.w); ac3=fmaf(f,a[8*ci+7],ac3);
        }
      } else if constexpr (FM==1){
        const float* wr = (const float*)Wg + (size_t)j*ldw + 8*kq;
#pragma unroll
        for (int ci=0; ci<NC; ci++){
          const float4 w0 = *(const float4*)(wr + 32*ci);
          const float4 w1 = *(const float4*)(wr + 32*ci + 4);
          ac0=fmaf(w0.x,a[8*ci+0],ac0); ac1=fmaf(w0.y,a[8*ci+1],ac1);
          ac2=fmaf(w0.z,a[8*ci+2],ac2); ac3=fmaf(w0.w,a[8*ci+3],ac3);
          ac0=fmaf(w1.x,a[8*ci+4],ac0); ac1=fmaf(w1.y,a[8*ci+5],ac1);
          ac2=fmaf(w1.z,a[8*ci+6],ac2); ac3=fmaf(w1.w,a[8*ci+7],ac3);
        }
      } else {
        const u16* wr = (const u16*)Wg + (size_t)j*ldw + 8*kq;
#pragma unroll
        for (int ci=0; ci<NC; ci++){
          const uint4 w = *(const uint4*)(wr + 32*ci);
          float f;
          f=lo2f(w.x); ac0=fmaf(f,a[8*ci+0],ac0);
          f=hi2f(w.x); ac1=fmaf(f,a[8*ci+1],ac1);
          f=lo2f(w.y); ac2=fmaf(f,a[8*ci+2],ac2);
          f=hi2f(w.y); ac3=fmaf(f,a[8*ci+3],ac3);
          f=lo2f(w.z); ac0=fmaf(f,a[8*ci+4],ac0);
          f=hi2f(w.z); ac1=fmaf(f,a[8*ci+5],ac1);
          f=lo2f(w.w); ac2=fmaf(f,a[8*ci+6],ac2);
          f=hi2f(w.w); ac3=fmaf(f,a[8*ci+7],ac3);
        }
      }
    }
    float acc = (ac0+ac1)+(ac2+ac3);
    acc += __shfl_xor(acc,1,64); acc += __shfl_xor(acc,2,64);
    if (act && kq==0) epi(j, acc);
  }
  __syncthreads();
}

template<int FM>
__device__ __forceinline__ void stage_b(const void* src, float* dst, int n, int tid){
  for (int i=tid;i<n;i+=512) dst[i] = ldf<FM>(src,i);
}

template<int FM>
__device__ __forceinline__ void run_all(
    SMState& sm, float* smb, u16* Ash, const int mode,
    const void* Tp, const void* Xp, const void* Mp, const void* Ap,
    const void* Wemb, const void* bemb, const void* Wproj, const void* bproj,
    const void* eW1, const void* eb1, const void* eW2, const void* eb2,
    const void* dW1, const void* db1, const void* dW2, const void* db2,
    const void* Wih, const void* Whh, const void* bih, const void* bhh,
    void* Out)
{
  const int tid  = threadIdx.x;
  const int lane = tid & 63;
  const int kq   = lane & 3;
  const int j0   = (tid>>6)*16 + (lane>>2);
  const int r0   = blockIdx.x;
  constexpr int WB = NDIM*NDIM*(FM?4:2);

  if (FM==0){
    const uint4* src = (const uint4*)Ap;
    for (int i=tid;i<2048;i+=512){
      const int row=i>>4, c=i&15;
      *(uint4*)((char*)Ash + 2*(size_t)row*A_STRIDE_E + 16*c) = src[i];
    }
  }
  __syncthreads();

  if (tid < NDIM) sm.e[tid] = smb[OBEMB+tid];
  __syncthreads();
#pragma unroll 1
  for (int ib=0; ib<NBLK; ib++){
    const void* W1 = (const char*)eW1 + (size_t)ib*WB;
    const void* W2 = (const char*)eW2 + (size_t)ib*WB;
    const int bo = ib*NDIM;
    mv<FM,32,128,false>(W1, nullptr, NDIM, sm.e, kq, j0, [&](int j,float s){
      sm.h[j]=fmaxf(s+smb[OEB1+bo+j],0.f); });
    mv<FM,32,128,false>(W2, nullptr, NDIM, sm.h, kq, j0, [&](int j,float s){
      sm.e[j]+=s+smb[OEB2+bo+j]; });
  }

#pragma unroll 1
  for (int t=0; t<TLEN; t++){
    float xv_r = 0.f; int m_r = 0;
    if (tid < DDIM){
      const size_t idx = (size_t)r0*TLEN*DDIM + (size_t)t*DDIM + tid;
      if      (mode==0) m_r = ((const u16*)Mp)[idx] != 0;
      else if (mode==1) m_r = ((const u32*)Mp)[idx] != 0;
      else if (mode==2) m_r = ((const unsigned char*)Mp)[idx] != 0;
      else              m_r = ((const int*)Mp)[idx] != 0;
      xv_r = ldf<FM>(Xp, (int)idx);
    }

    {
      float dtv = 0.f;
      if (t>0) dtv = ldf<FM>(Tp,t) - ldf<FM>(Tp,t-1);
      if (tid < NDIM){ const float z=sm.e[tid]; sm.V0[tid]=z; sm.zh[tid]=z; }
      __syncthreads();
#pragma unroll 1
      for (int k=1;k<=TAYLOR;k++){
        const float sc = dtv/(float)k;
        const float* Vin = (k&1)?sm.V0:sm.V1;
        float*      Vout = (k&1)?sm.V1:sm.V0;
        if constexpr (FM==0){
          mv<0,32,128,true>(nullptr, Ash, NDIM, Vin, kq, j0, [&](int j,float s){
            const float v=s*sc; Vout[j]=v; sm.zh[j]+=v; });
        } else {
          mv<1,32,128,false>(Ap, nullptr, NDIM, Vin, kq, j0, [&](int j,float s){
            const float v=s*sc; Vout[j]=v; sm.zh[j]+=v; });
        }
      }
    }

#pragma unroll 1
    for (int ib=0; ib<NBLK; ib++){
      const void* W1 = (const char*)dW1 + (size_t)ib*WB;
      const void* W2 = (const char*)dW2 + (size_t)ib*WB;
      const int bo = ib*NDIM;
      mv<FM,32,128,false>(W1, nullptr, NDIM, sm.zh, kq, j0, [&](int j,float s){
        sm.h[j]=fmaxf(s+smb[ODB1+bo+j],0.f); });
      mv<FM,32,128,false>(W2, nullptr, NDIM, sm.h, kq, j0, [&](int j,float s){
        sm.zh[j]+=s+smb[ODB2+bo+j]; });
    }

    mv<FM,32,96,false>(Wproj, nullptr, NDIM, sm.zh, kq, j0, [&](int j,float s){
      sm.xpre[j]=s+smb[OBPROJ+j]; });

    if (tid < DDIM){
      sm.u[tid]      = m_r ? xv_r : sm.xpre[tid];
      sm.u[DDIM+tid] = m_r ? 1.f : 0.f;
    }
    __syncthreads();

    mv<FM,48,288,false>(Wih, nullptr, 2*DDIM, sm.u, kq, j0, [&](int j,float s){
      sm.gi[j]=s+smb[OBIH+j]; });
    mv<FM,24,288,false>(Whh, nullptr, DDIM, sm.xpre, kq, j0, [&](int j,float s){
      sm.gh[j]=s+smb[OBHH+j]; });

    if (tid < DDIM){
      const int d = tid;
      const float ir=sm.gi[d], iz=sm.gi[DDIM+d], in_=sm.gi[2*DDIM+d];
      const float hr=sm.gh[d], hz=sm.gh[DDIM+d], hn=sm.gh[2*DDIM+d];
      const float rg = 1.f/(1.f+__expf(-(ir+hr)));
      const float zg = 1.f/(1.f+__expf(-(iz+hz)));
      const float ag = in_ + rg*hn;
      const float e2 = __expf(2.f*ag);
      const float ng = 1.f - 2.f/(e2+1.f);
      const float xp = sm.xpre[d];
      const float xq = (1.f-zg)*ng + zg*xp;
      sm.xpost[d] = xq;
      const size_t idx = (size_t)r0*TLEN*DDIM + (size_t)t*DDIM + d;
      if constexpr (FM==1) ((float*)Out)[idx] = xq;
      else ((__hip_bfloat16*)Out)[idx] = __float2bfloat16(xq);
    }
    __syncthreads();

    mv<FM,24,128,false>(Wemb, nullptr, DDIM, sm.xpost, kq, j0, [&](int j,float s){
      sm.e[j]=s+smb[OBEMB+j]; });

#pragma unroll 1
    for (int ib=0; ib<NBLK; ib++){
      const void* W1 = (const char*)eW1 + (size_t)ib*WB;
      const void* W2 = (const char*)eW2 + (size_t)ib*WB;
      const int bo = ib*NDIM;
      mv<FM,32,128,false>(W1, nullptr, NDIM, sm.e, kq, j0, [&](int j,float s){
        sm.h[j]=fmaxf(s+smb[OEB1+bo+j],0.f); });
      mv<FM,32,128,false>(W2, nullptr, NDIM, sm.h, kq, j0, [&](int j,float s){
        sm.e[j]+=s+smb[OEB2+bo+j]; });
    }
  }
}

__global__ __launch_bounds__(512, 4)
void linode_kernel(const void* Tp, const void* Xp, const void* Mp, const void* Ap,
                   const void* Wemb, const void* bemb, const void* Wproj, const void* bproj,
                   const void* eW1, const void* eb1, const void* eW2, const void* eb2,
                   const void* dW1, const void* db1, const void* dW2, const void* db2,
                   const void* Wih, const void* Whh, const void* bih, const void* bhh,
                   const u16* Ep, const int useE, void* Out)
{
  __shared__ SMState sm;
  __shared__ float smb[NBIAS];
  __shared__ __align__(16) u16 Ash[NDIM*A_STRIDE_E];
  __shared__ int s_f[4];
  const int tid = threadIdx.x;

  if (tid < 4) s_f[tid] = 0;
  __syncthreads();
  if (tid == 0){
    int all0 = 1;
    for (int k=0;k<8;k++) all0 &= (((const u32*)Ap)[129*k] == 0u);
    s_f[3] = all0;
  }
  {
    const u32* mw = (const u32*)Mp;
    int fb=0, ff=0, fg=0;
    for (int i=tid;i<2048;i+=512){
      const u32 w = mw[i];
      if (w == 0x3F803F80u) fb = 1;
      if ((w&0xFFFFu)==0x3F80u || (w>>16)==0x3F80u) ff = 1;
      if (w > 1u) fg = 1;
    }
    if (fb) atomicOr(&s_f[0],1);
    if (ff) atomicOr(&s_f[1],1);
    if (fg) atomicOr(&s_f[2],1);
  }
  __syncthreads();
  const int mode = s_f[0] ? 0 : (s_f[1] ? 1 : (s_f[2] ? 2 : 3));
  const int f32m = s_f[3];
  __syncthreads();

  if (!f32m && useE){
    // stage biases then run the pipelined path
    stage_b<0>(eb1, smb+OEB1, NBLK*NDIM, tid);
    stage_b<0>(eb2, smb+OEB2, NBLK*NDIM, tid);
    stage_b<0>(db1, smb+ODB1, NBLK*NDIM, tid);
    stage_b<0>(db2, smb+ODB2, NBLK*NDIM, tid);
    stage_b<0>(bemb, smb+OBEMB, NDIM, tid);
    stage_b<0>(bproj, smb+OBPROJ, DDIM, tid);
    stage_b<0>(bih, smb+OBIH, 3*DDIM, tid);
    stage_b<0>(bhh, smb+OBHH, 3*DDIM, tid);
    __syncthreads();
    run_pipe(sm, smb, mode, Xp, Mp,
             (const u16*)Wemb, (const u16*)Wproj,
             (const u16*)eW1, (const u16*)eW2,
             (const u16*)dW1, (const u16*)dW2,
             (const u16*)Wih, (const u16*)Whh,
             Ep, (__hip_bfloat16*)Out);
  } else if (f32m){
    stage_b<1>(eb1, smb+OEB1, NBLK*NDIM, tid);
    stage_b<1>(eb2, smb+OEB2, NBLK*NDIM, tid);
    stage_b<1>(db1, smb+ODB1, NBLK*NDIM, tid);
    stage_b<1>(db2, smb+ODB2, NBLK*NDIM, tid);
    stage_b<1>(bemb, smb+OBEMB, NDIM, tid);
    stage_b<1>(bproj, smb+OBPROJ, DDIM, tid);
    stage_b<1>(bih, smb+OBIH, 3*DDIM, tid);
    stage_b<1>(bhh, smb+OBHH, 3*DDIM, tid);
    __syncthreads();
    run_all<1>(sm, smb, Ash, mode, Tp, Xp, Mp, Ap, Wemb, bemb, Wproj, bproj,
               eW1, eb1, eW2, eb2, dW1, db1, dW2, db2, Wih, Whh, bih, bhh, Out);
  } else {
    stage_b<0>(eb1, smb+OEB1, NBLK*NDIM, tid);
    stage_b<0>(eb2, smb+OEB2, NBLK*NDIM, tid);
    stage_b<0>(db1, smb+ODB1, NBLK*NDIM, tid);
    stage_b<0>(db2, smb+ODB2, NBLK*NDIM, tid);
    stage_b<0>(bemb, smb+OBEMB, NDIM, tid);
    stage_b<0>(bproj, smb+OBPROJ, DDIM, tid);
    stage_b<0>(bih, smb+OBIH, 3*DDIM, tid);
    stage_b<0>(bhh, smb+OBHH, 3*DDIM, tid);
    __syncthreads();
    run_all<0>(sm, smb, Ash, mode, Tp, Xp, Mp, Ap, Wemb, bemb, Wproj, bproj,
               eW1, eb1, eW2, eb2, dW1, db1, dW2, db2, Wih, Whh, bih, bhh, Out);
  }
}

extern "C" void kernel_launch(void* const* d_in, const int* in_sizes, int n_in,
                              void* d_out, int out_size, void* d_ws, size_t ws_size,
                              hipStream_t stream)
{
  (void)in_sizes; (void)n_in; (void)out_size;
  const int useE = (ws_size >= (size_t)TLEN*NDIM*NDIM*2) ? 1 : 0;
  if (useE)
    hipLaunchKernelGGL(expm_kernel, dim3(2*TLEN), dim3(256), 0, stream,
                       d_in[0], d_in[3], (u16*)d_ws);
  hipLaunchKernelGGL(linode_kernel, dim3(NBATCH), dim3(512), 0, stream,
                     d_in[0], d_in[1], d_in[2], d_in[3],
                     d_in[4], d_in[5], d_in[6], d_in[7],
                     d_in[8], d_in[9], d_in[10], d_in[11],
                     d_in[12], d_in[13], d_in[14], d_in[15],
                     d_in[16], d_in[17], d_in[18], d_in[19],
                     (const u16*)d_ws, useE, d_out);
}

// Round 6
// 5151.507 us; speedup vs baseline: 1.3391x; 1.0083x over previous
//
#include <hip/hip_runtime.h>
#include <hip/hip_bf16.h>

// LinODEnet forward, MI355X — r6: raw barrier (no vmcnt drain).
// r5 post-mortem: cross-barrier weight prefetch was DEFEATED because
// __syncthreads() lowers to s_waitcnt vmcnt(0) lgkmcnt(0); s_barrier —
// the prefetched loads were drained at barrier entry (stall moved, not
// removed). r6 replaces main-loop barriers with
//   asm("s_waitcnt lgkmcnt(0); s_barrier" ::: "memory")
// so global weight loads stay in flight ACROSS the barrier (AITER/HK
// counted-vmcnt pattern); the compiler's automatic vmcnt(N) wait at the
// point of USE picks them up a full stage later.
// Keeps: expm(A*dt) precompute into d_ws, 512 thr/block, 1 row/block,
// biases in LDS, cross-stage uint4 wp[6] prefetch, dtype auto-detect
// with Taylor/f32 fallback paths (those keep plain __syncthreads).

#define NBATCH 512
#define TLEN 128
#define DDIM 96
#define NDIM 128
#define NBLK 5
#define TAYLOR 8
#define A_STRIDE_E 136   // bf16 elems; 272B row

typedef unsigned short u16;
typedef unsigned int u32;

__device__ __forceinline__ float bf2f(u16 u){ union{u32 i; float f;} v; v.i=((u32)u)<<16; return v.f; }
__device__ __forceinline__ float lo2f(u32 w){ union{u32 i; float f;} v; v.i=w<<16; return v.f; }
__device__ __forceinline__ float hi2f(u32 w){ union{u32 i; float f;} v; v.i=w&0xFFFF0000u; return v.f; }
__device__ __forceinline__ u16 f2bf(float x){ union{float f;u32 i;} v; v.f=x; u32 r=v.i+0x7FFF+((v.i>>16)&1); return (u16)(r>>16); }

// barrier that drains LDS ops only — global loads stay in flight
__device__ __forceinline__ void barrier_l(){
  asm volatile("s_waitcnt lgkmcnt(0)\n\ts_barrier" ::: "memory");
}

template<int FM>
__device__ __forceinline__ float ldf(const void* p, int i){
  if constexpr (FM==1) return ((const float*)p)[i];
  else return bf2f(((const u16*)p)[i]);
}

// bias LDS offsets (floats)
#define OEB1 0
#define OEB2 640
#define ODB1 1280
#define ODB2 1920
#define OBEMB 2560
#define OBPROJ 2688
#define OBIH 2784
#define OBHH 3072
#define NBIAS 3360

struct __align__(16) SMState {
  float e[NDIM];
  float V0[NDIM];
  float V1[NDIM];
  float zh[NDIM];
  float h[NDIM];
  float xpre[DDIM];
  float u[2*DDIM];
  float gi[3*DDIM];
  float gh[3*DDIM];
  float xpost[DDIM];
};

// ================= expm precompute (unchanged) =================
__global__ __launch_bounds__(256, 1)
void expm_kernel(const void* Tp, const void* Ap, u16* Ews)
{
  __shared__ int sf;
  __shared__ __align__(16) u16 Ash2[NDIM*A_STRIDE_E];
  __shared__ __align__(16) float V[2][64*132];
  const int tid = threadIdx.x;
  if (tid==0){
    int all0=1;
    for (int k=0;k<8;k++) all0 &= (((const u32*)Ap)[129*k]==0u);
    sf = all0;
  }
  __syncthreads();
  if (sf) return;

  const int t = blockIdx.x >> 1, half = blockIdx.x & 1;
  float dtv = 0.f;
  if (t>0) dtv = bf2f(((const u16*)Tp)[t]) - bf2f(((const u16*)Tp)[t-1]);
  {
    const uint4* src = (const uint4*)Ap;
    for (int i=tid;i<2048;i+=256){
      const int row=i>>4, c=i&15;
      *(uint4*)((char*)Ash2 + 2*(size_t)row*A_STRIDE_E + 16*c) = src[i];
    }
  }
  const int c2 = tid & 31, rh = tid >> 5;
  const int j0r = rh*16;
  const int lc0 = 2*c2, lc1 = lc0+1;
  const int gc0 = half*64 + lc0, gc1 = gc0+1;

  float acc0[16], acc1[16];
#pragma unroll
  for (int jj=0;jj<16;jj++){
    const int kk = j0r+jj;
    const float i0 = (kk==gc0)?1.f:0.f, i1 = (kk==gc1)?1.f:0.f;
    acc0[jj]=i0; acc1[jj]=i1;
    V[0][lc0*132+kk]=i0; V[0][lc1*132+kk]=i1;
  }
  __syncthreads();
  int cur=0;
#pragma unroll 1
  for (int k=1;k<=8;k++){
    const float sc = dtv/(float)k;
    float o0[16], o1[16];
#pragma unroll
    for (int jj=0;jj<16;jj++){ o0[jj]=0.f; o1[jj]=0.f; }
#pragma unroll 1
    for (int kb=0;kb<16;kb++){
      const float4 va0 = *(const float4*)&V[cur][lc0*132+kb*8];
      const float4 vb0 = *(const float4*)&V[cur][lc0*132+kb*8+4];
      const float4 va1 = *(const float4*)&V[cur][lc1*132+kb*8];
      const float4 vb1 = *(const float4*)&V[cur][lc1*132+kb*8+4];
      const float v0[8]={va0.x,va0.y,va0.z,va0.w,vb0.x,vb0.y,vb0.z,vb0.w};
      const float v1[8]={va1.x,va1.y,va1.z,va1.w,vb1.x,vb1.y,vb1.z,vb1.w};
#pragma unroll
      for (int jj=0;jj<16;jj++){
        const int j = j0r+jj;
        const uint4 w = *(const uint4*)((const char*)Ash2 + 2*(size_t)j*A_STRIDE_E + 16*kb);
        float f;
        f=lo2f(w.x); o0[jj]=fmaf(f,v0[0],o0[jj]); o1[jj]=fmaf(f,v1[0],o1[jj]);
        f=hi2f(w.x); o0[jj]=fmaf(f,v0[1],o0[jj]); o1[jj]=fmaf(f,v1[1],o1[jj]);
        f=lo2f(w.y); o0[jj]=fmaf(f,v0[2],o0[jj]); o1[jj]=fmaf(f,v1[2],o1[jj]);
        f=hi2f(w.y); o0[jj]=fmaf(f,v0[3],o0[jj]); o1[jj]=fmaf(f,v1[3],o1[jj]);
        f=lo2f(w.z); o0[jj]=fmaf(f,v0[4],o0[jj]); o1[jj]=fmaf(f,v1[4],o1[jj]);
        f=hi2f(w.z); o0[jj]=fmaf(f,v0[5],o0[jj]); o1[jj]=fmaf(f,v1[5],o1[jj]);
        f=lo2f(w.w); o0[jj]=fmaf(f,v0[6],o0[jj]); o1[jj]=fmaf(f,v1[6],o1[jj]);
        f=hi2f(w.w); o0[jj]=fmaf(f,v0[7],o0[jj]); o1[jj]=fmaf(f,v1[7],o1[jj]);
      }
    }
    __syncthreads();
#pragma unroll
    for (int jj=0;jj<16;jj++){
      const int j=j0r+jj;
      const float s0=o0[jj]*sc, s1=o1[jj]*sc;
      acc0[jj]+=s0; acc1[jj]+=s1;
      V[cur^1][lc0*132+j]=s0; V[cur^1][lc1*132+j]=s1;
    }
    __syncthreads();
    cur^=1;
  }
#pragma unroll
  for (int jj=0;jj<16;jj++){
    const int j=j0r+jj;
    const u32 pk = (u32)f2bf(acc0[jj]) | ((u32)f2bf(acc1[jj])<<16);
    *((u32*)(Ews + (size_t)t*NDIM*NDIM + (size_t)j*NDIM + gc0)) = pk;
  }
}

// ================= pipelined bf16 helpers =================
template<int NC>
__device__ __forceinline__ void wload(uint4* wp, const u16* W, int ldw_e, int j, int kq){
  const u16* wr = W + (size_t)j*ldw_e + 8*kq;
#pragma unroll
  for (int ci=0; ci<NC; ci++) wp[ci] = *(const uint4*)(wr + 32*ci);
}
template<int S>
__device__ __forceinline__ void aload(float* a, const float* in, int kq){
  const float* p = in + 8*kq;
#pragma unroll
  for (int ci=0; ci<S/8; ci++){
    float4 v0 = *(const float4*)(p + 32*ci);
    float4 v1 = *(const float4*)(p + 32*ci + 4);
    a[8*ci+0]=v0.x; a[8*ci+1]=v0.y; a[8*ci+2]=v0.z; a[8*ci+3]=v0.w;
    a[8*ci+4]=v1.x; a[8*ci+5]=v1.y; a[8*ci+6]=v1.z; a[8*ci+7]=v1.w;
  }
}
template<int NC>
__device__ __forceinline__ float dotw(const uint4* wp, const float* a){
  float ac0=0.f,ac1=0.f,ac2=0.f,ac3=0.f;
#pragma unroll
  for (int ci=0; ci<NC; ci++){
    const uint4 w = wp[ci]; float f;
    f=lo2f(w.x); ac0=fmaf(f,a[8*ci+0],ac0);
    f=hi2f(w.x); ac1=fmaf(f,a[8*ci+1],ac1);
    f=lo2f(w.y); ac2=fmaf(f,a[8*ci+2],ac2);
    f=hi2f(w.y); ac3=fmaf(f,a[8*ci+3],ac3);
    f=lo2f(w.z); ac0=fmaf(f,a[8*ci+4],ac0);
    f=hi2f(w.z); ac1=fmaf(f,a[8*ci+5],ac1);
    f=lo2f(w.w); ac2=fmaf(f,a[8*ci+6],ac2);
    f=hi2f(w.w); ac3=fmaf(f,a[8*ci+7],ac3);
  }
  return (ac0+ac1)+(ac2+ac3);
}
template<int NC>
__device__ __forceinline__ float dotl(const u16* W, int ldw_e, int j, int kq, const float* a){
  uint4 wl[NC]; wload<NC>(wl,W,ldw_e,j,kq); return dotw<NC>(wl,a);
}
__device__ __forceinline__ float red4(float x){
  x += __shfl_xor(x,1,64); x += __shfl_xor(x,2,64); return x;
}

// ================= pipelined main path (bf16 + precomputed E) =================
__device__ __forceinline__ void run_pipe(
    SMState& sm, float* smb, const int mode,
    const void* Xp, const void* Mp,
    const u16* Wemb, const u16* Wproj,
    const u16* eW1, const u16* eW2,
    const u16* dW1, const u16* dW2,
    const u16* Wih, const u16* Whh,
    const u16* Ep, __hip_bfloat16* Out)
{
  const int tid  = threadIdx.x;
  const int lane = tid & 63;
  const int kq   = lane & 3;
  const int j0   = (tid>>6)*16 + (lane>>2);   // 0..127
  const int r0   = blockIdx.x;
  const bool epl = (kq==0);

  // ---- z0 = enc(embed(0)); embed(0)=b_emb (once; plain barriers fine) ----
  if (tid < NDIM) sm.e[tid] = smb[OBEMB+tid];
  __syncthreads();
  {
    float a[32];
#pragma unroll 1
    for (int ib=0; ib<NBLK; ib++){
      aload<32>(a, sm.e, kq);
      float acc = red4(dotl<4>(eW1+ib*NDIM*NDIM, NDIM, j0, kq, a));
      if (epl) sm.h[j0]=fmaxf(acc+smb[OEB1+ib*NDIM+j0],0.f);
      __syncthreads();
      aload<32>(a, sm.h, kq);
      acc = red4(dotl<4>(eW2+ib*NDIM*NDIM, NDIM, j0, kq, a));
      if (epl) sm.e[j0]+=acc+smb[OEB2+ib*NDIM+j0];
      __syncthreads();
    }
  }

  uint4 wp[6];                      // pipelined weight buffer (pass-0 of next stage)
  wload<4>(wp, Ep, NDIM, j0, kq);   // prime with E_0

#pragma unroll 1
  for (int t=0; t<TLEN; t++){
    // X/mask prefetch (stays in flight until proj epilogue — no drain now)
    float xv_r = 0.f; int m_r = 0;
    if (epl && j0 < DDIM){
      const size_t idx = (size_t)r0*TLEN*DDIM + (size_t)t*DDIM + j0;
      if      (mode==0) m_r = ((const u16*)Mp)[idx] != 0;
      else if (mode==1) m_r = ((const u32*)Mp)[idx] != 0;
      else if (mode==2) m_r = ((const unsigned char*)Mp)[idx] != 0;
      else              m_r = ((const int*)Mp)[idx] != 0;
      xv_r = bf2f(((const u16*)Xp)[idx]);
    }

    // S0: zh = E_t e
    {
      float a[32]; aload<32>(a, sm.e, kq);
      float acc = dotw<4>(wp, a);
      wload<4>(wp, dW1, NDIM, j0, kq);                   // prefetch dec W1(0)
      acc = red4(acc);
      if (epl) sm.zh[j0] = acc;
    }
    barrier_l();

    // decoder resnet
#pragma unroll 1
    for (int ib=0; ib<NBLK; ib++){
      float a[32];
      aload<32>(a, sm.zh, kq);
      float acc = dotw<4>(wp, a);
      wload<4>(wp, dW2+ib*NDIM*NDIM, NDIM, j0, kq);      // prefetch dec W2(ib)
      acc = red4(acc);
      if (epl) sm.h[j0]=fmaxf(acc+smb[ODB1+ib*NDIM+j0],0.f);
      barrier_l();
      aload<32>(a, sm.h, kq);
      acc = dotw<4>(wp, a);
      if (ib<NBLK-1) wload<4>(wp, dW1+(ib+1)*NDIM*NDIM, NDIM, j0, kq);
      else           wload<4>(wp, Wproj, NDIM, (j0<DDIM?j0:DDIM-1), kq);
      acc = red4(acc);
      if (epl) sm.zh[j0]+=acc+smb[ODB2+ib*NDIM+j0];
      barrier_l();
    }

    // proj + fused GRU-input write
    {
      float a[32]; aload<32>(a, sm.zh, kq);
      float acc = dotw<4>(wp, a);
      wload<6>(wp, Wih, 2*DDIM, j0, kq);                 // prefetch gi pass0
      acc = red4(acc);
      if (epl && j0 < DDIM){
        const float xp = acc + smb[OBPROJ+j0];
        sm.xpre[j0] = xp;
        sm.u[j0]      = m_r ? xv_r : xp;
        sm.u[DDIM+j0] = m_r ? 1.f : 0.f;
      }
    }
    barrier_l();

    // gi = u @ Wih^T + bih  (288 outputs, 3 passes)
    {
      float a[48]; aload<48>(a, sm.u, kq);
      float g0 = dotw<6>(wp, a);
      wload<3>(wp, Whh, DDIM, j0, kq);                   // prefetch gh pass0
      float g1 = dotl<6>(Wih, 2*DDIM, 128+j0, kq, a);
      float g2 = (j0<32) ? dotl<6>(Wih, 2*DDIM, 256+j0, kq, a) : 0.f;
      g0=red4(g0); g1=red4(g1); g2=red4(g2);
      if (epl){
        sm.gi[j0]     = g0 + smb[OBIH+j0];
        sm.gi[128+j0] = g1 + smb[OBIH+128+j0];
        if (j0<32) sm.gi[256+j0] = g2 + smb[OBIH+256+j0];
      }
    }
    barrier_l();

    // gh = xpre @ Whh^T + bhh  (288 outputs, 3 passes)
    {
      float a[24]; aload<24>(a, sm.xpre, kq);
      float g0 = dotw<3>(wp, a);
      wload<3>(wp, Wemb, DDIM, j0, kq);                  // prefetch emb
      float g1 = dotl<3>(Whh, DDIM, 128+j0, kq, a);
      float g2 = (j0<32) ? dotl<3>(Whh, DDIM, 256+j0, kq, a) : 0.f;
      g0=red4(g0); g1=red4(g1); g2=red4(g2);
      if (epl){
        sm.gh[j0]     = g0 + smb[OBHH+j0];
        sm.gh[128+j0] = g1 + smb[OBHH+128+j0];
        if (j0<32) sm.gh[256+j0] = g2 + smb[OBHH+256+j0];
      }
    }
    barrier_l();

    // GRU gates -> xhat_post; store output
    if (tid < DDIM){
      const int d = tid;
      const float ir=sm.gi[d], iz=sm.gi[DDIM+d], in_=sm.gi[2*DDIM+d];
      const float hr=sm.gh[d], hz=sm.gh[DDIM+d], hn=sm.gh[2*DDIM+d];
      const float rg = 1.f/(1.f+__expf(-(ir+hr)));
      const float zg = 1.f/(1.f+__expf(-(iz+hz)));
      const float ag = in_ + rg*hn;
      const float e2 = __expf(2.f*ag);
      const float ng = 1.f - 2.f/(e2+1.f);
      const float xp = sm.xpre[d];
      const float xq = (1.f-zg)*ng + zg*xp;
      sm.xpost[d] = xq;
      const size_t idx = (size_t)r0*TLEN*DDIM + (size_t)t*DDIM + d;
      Out[idx] = __float2bfloat16(xq);
    }
    barrier_l();

    // e = embed(xpost)
    {
      float a[24]; aload<24>(a, sm.xpost, kq);
      float acc = dotw<3>(wp, a);
      wload<4>(wp, eW1, NDIM, j0, kq);                   // prefetch enc W1(0)
      acc = red4(acc);
      if (epl) sm.e[j0] = acc + smb[OBEMB+j0];
    }
    barrier_l();

    // encoder resnet -> next z
#pragma unroll 1
    for (int ib=0; ib<NBLK; ib++){
      float a[32];
      aload<32>(a, sm.e, kq);
      float acc = dotw<4>(wp, a);
      wload<4>(wp, eW2+ib*NDIM*NDIM, NDIM, j0, kq);      // prefetch enc W2(ib)
      acc = red4(acc);
      if (epl) sm.h[j0]=fmaxf(acc+smb[OEB1+ib*NDIM+j0],0.f);
      barrier_l();
      aload<32>(a, sm.h, kq);
      acc = dotw<4>(wp, a);
      if (ib<NBLK-1) wload<4>(wp, eW1+(ib+1)*NDIM*NDIM, NDIM, j0, kq);
      else {
        const u16* En = Ep + (size_t)((t+1<TLEN)?(t+1):t)*NDIM*NDIM;
        wload<4>(wp, En, NDIM, j0, kq);                  // prefetch E_{t+1}
      }
      acc = red4(acc);
      if (epl) sm.e[j0]+=acc+smb[OEB2+ib*NDIM+j0];
      barrier_l();
    }
  }
}

// ================= fallback matvec (f32 inputs or no workspace) =================
template<int FM, int S, int NO, bool WL, class EPI>
__device__ __forceinline__ void mv(const void* __restrict__ Wg, const u16* __restrict__ Wl,
                                   const int ldw, const float* __restrict__ in,
                                   const int kq, const int j0, EPI epi)
{
  constexpr int NC = S/8;
  constexpr int P = (NO+127)/128;
  constexpr bool full = (NO%128==0);
  float a[S];
  {
    const float* p = in + 8*kq;
#pragma unroll
    for (int ci=0; ci<NC; ci++){
      float4 v0 = *(const float4*)(p + 32*ci);
      float4 v1 = *(const float4*)(p + 32*ci + 4);
      a[8*ci+0]=v0.x; a[8*ci+1]=v0.y; a[8*ci+2]=v0.z; a[8*ci+3]=v0.w;
      a[8*ci+4]=v1.x; a[8*ci+5]=v1.y; a[8*ci+6]=v1.z; a[8*ci+7]=v1.w;
    }
  }
#pragma unroll
  for (int pp=0; pp<P; pp++){
    const int j = pp*128 + j0;
    const bool act = full || (j < NO);
    float ac0=0.f, ac1=0.f, ac2=0.f, ac3=0.f;
    if (act){
      if constexpr (WL){
        const char* wr = (const char*)Wl + 2*(size_t)j*A_STRIDE_E + 16*kq;
#pragma unroll
        for (int ci=0; ci<NC; ci++){
          const uint4 w = *(const uint4*)(wr + 64*ci);
          float f;
          f=lo2f(w.x); ac0=fmaf(f,a[8*ci+0],ac0);
          f=hi2f(w.x); ac1=fmaf(f,a[8*ci+1],ac1);
          f=lo2f(w.y); ac2=fmaf(f,a[8*ci+2],ac2);
          f=hi2f(w.y); ac3=fmaf(f,a[8*ci+3],ac3);
          f=lo2f(w.z); ac0=fmaf(f,a[8*ci+4],ac0);
          f=hi2f(w.z); ac1=fmaf(f,a[8*ci+5],ac1);
          f=lo2f(w.w); ac2=fmaf(f,a[8*ci+6],ac2);
          f=hi2f(w.w); ac3=fmaf(f,a[8*ci+7],ac3);
        }
      } else if constexpr (FM==1){
        const float* wr = (const float*)Wg + (size_t)j*ldw + 8*kq;
#pragma unroll
        for (int ci=0; ci<NC; ci++){
          const float4 w0 = *(const float4*)(wr + 32*ci);
          const float4 w1 = *(const float4*)(wr + 32*ci + 4);
          ac0=fmaf(w0.x,a[8*ci+0],ac0); ac1=fmaf(w0.y,a[8*ci+1],ac1);
          ac2=fmaf(w0.z,a[8*ci+2],ac2); ac3=fmaf(w0.w,a[8*ci+3],ac3);
          ac0=fmaf(w1.x,a[8*ci+4],ac0); ac1=fmaf(w1.y,a[8*ci+5],ac1);
          ac2=fmaf(w1.z,a[8*ci+6],ac2); ac3=fmaf(w1.w,a[8*ci+7],ac3);
        }
      } else {
        const u16* wr = (const u16*)Wg + (size_t)j*ldw + 8*kq;
#pragma unroll
        for (int ci=0; ci<NC; ci++){
          const uint4 w = *(const uint4*)(wr + 32*ci);
          float f;
          f=lo2f(w.x); ac0=fmaf(f,a[8*ci+0],ac0);
          f=hi2f(w.x); ac1=fmaf(f,a[8*ci+1],ac1);
          f=lo2f(w.y); ac2=fmaf(f,a[8*ci+2],ac2);
          f=hi2f(w.y); ac3=fmaf(f,a[8*ci+3],ac3);
          f=lo2f(w.z); ac0=fmaf(f,a[8*ci+4],ac0);
          f=hi2f(w.z); ac1=fmaf(f,a[8*ci+5],ac1);
          f=lo2f(w.w); ac2=fmaf(f,a[8*ci+6],ac2);
          f=hi2f(w.w); ac3=fmaf(f,a[8*ci+7],ac3);
        }
      }
    }
    float acc = (ac0+ac1)+(ac2+ac3);
    acc += __shfl_xor(acc,1,64); acc += __shfl_xor(acc,2,64);
    if (act && kq==0) epi(j, acc);
  }
  __syncthreads();
}

template<int FM>
__device__ __forceinline__ void stage_b(const void* src, float* dst, int n, int tid){
  for (int i=tid;i<n;i+=512) dst[i] = ldf<FM>(src,i);
}

template<int FM>
__device__ __forceinline__ void run_all(
    SMState& sm, float* smb, u16* Ash, const int mode,
    const void* Tp, const void* Xp, const void* Mp, const void* Ap,
    const void* Wemb, const void* bemb, const void* Wproj, const void* bproj,
    const void* eW1, const void* eb1, const void* eW2, const void* eb2,
    const void* dW1, const void* db1, const void* dW2, const void* db2,
    const void* Wih, const void* Whh, const void* bih, const void* bhh,
    void* Out)
{
  const int tid  = threadIdx.x;
  const int lane = tid & 63;
  const int kq   = lane & 3;
  const int j0   = (tid>>6)*16 + (lane>>2);
  const int r0   = blockIdx.x;
  constexpr int WB = NDIM*NDIM*(FM?4:2);

  if (FM==0){
    const uint4* src = (const uint4*)Ap;
    for (int i=tid;i<2048;i+=512){
      const int row=i>>4, c=i&15;
      *(uint4*)((char*)Ash + 2*(size_t)row*A_STRIDE_E + 16*c) = src[i];
    }
  }
  __syncthreads();

  if (tid < NDIM) sm.e[tid] = smb[OBEMB+tid];
  __syncthreads();
#pragma unroll 1
  for (int ib=0; ib<NBLK; ib++){
    const void* W1 = (const char*)eW1 + (size_t)ib*WB;
    const void* W2 = (const char*)eW2 + (size_t)ib*WB;
    const int bo = ib*NDIM;
    mv<FM,32,128,false>(W1, nullptr, NDIM, sm.e, kq, j0, [&](int j,float s){
      sm.h[j]=fmaxf(s+smb[OEB1+bo+j],0.f); });
    mv<FM,32,128,false>(W2, nullptr, NDIM, sm.h, kq, j0, [&](int j,float s){
      sm.e[j]+=s+smb[OEB2+bo+j]; });
  }

#pragma unroll 1
  for (int t=0; t<TLEN; t++){
    float xv_r = 0.f; int m_r = 0;
    if (tid < DDIM){
      const size_t idx = (size_t)r0*TLEN*DDIM + (size_t)t*DDIM + tid;
      if      (mode==0) m_r = ((const u16*)Mp)[idx] != 0;
      else if (mode==1) m_r = ((const u32*)Mp)[idx] != 0;
      else if (mode==2) m_r = ((const unsigned char*)Mp)[idx] != 0;
      else              m_r = ((const int*)Mp)[idx] != 0;
      xv_r = ldf<FM>(Xp, (int)idx);
    }

    {
      float dtv = 0.f;
      if (t>0) dtv = ldf<FM>(Tp,t) - ldf<FM>(Tp,t-1);
      if (tid < NDIM){ const float z=sm.e[tid]; sm.V0[tid]=z; sm.zh[tid]=z; }
      __syncthreads();
#pragma unroll 1
      for (int k=1;k<=TAYLOR;k++){
        const float sc = dtv/(float)k;
        const float* Vin = (k&1)?sm.V0:sm.V1;
        float*      Vout = (k&1)?sm.V1:sm.V0;
        if constexpr (FM==0){
          mv<0,32,128,true>(nullptr, Ash, NDIM, Vin, kq, j0, [&](int j,float s){
            const float v=s*sc; Vout[j]=v; sm.zh[j]+=v; });
        } else {
          mv<1,32,128,false>(Ap, nullptr, NDIM, Vin, kq, j0, [&](int j,float s){
            const float v=s*sc; Vout[j]=v; sm.zh[j]+=v; });
        }
      }
    }

#pragma unroll 1
    for (int ib=0; ib<NBLK; ib++){
      const void* W1 = (const char*)dW1 + (size_t)ib*WB;
      const void* W2 = (const char*)dW2 + (size_t)ib*WB;
      const int bo = ib*NDIM;
      mv<FM,32,128,false>(W1, nullptr, NDIM, sm.zh, kq, j0, [&](int j,float s){
        sm.h[j]=fmaxf(s+smb[ODB1+bo+j],0.f); });
      mv<FM,32,128,false>(W2, nullptr, NDIM, sm.h, kq, j0, [&](int j,float s){
        sm.zh[j]+=s+smb[ODB2+bo+j]; });
    }

    mv<FM,32,96,false>(Wproj, nullptr, NDIM, sm.zh, kq, j0, [&](int j,float s){
      sm.xpre[j]=s+smb[OBPROJ+j]; });

    if (tid < DDIM){
      sm.u[tid]      = m_r ? xv_r : sm.xpre[tid];
      sm.u[DDIM+tid] = m_r ? 1.f : 0.f;
    }
    __syncthreads();

    mv<FM,48,288,false>(Wih, nullptr, 2*DDIM, sm.u, kq, j0, [&](int j,float s){
      sm.gi[j]=s+smb[OBIH+j]; });
    mv<FM,24,288,false>(Whh, nullptr, DDIM, sm.xpre, kq, j0, [&](int j,float s){
      sm.gh[j]=s+smb[OBHH+j]; });

    if (tid < DDIM){
      const int d = tid;
      const float ir=sm.gi[d], iz=sm.gi[DDIM+d], in_=sm.gi[2*DDIM+d];
      const float hr=sm.gh[d], hz=sm.gh[DDIM+d], hn=sm.gh[2*DDIM+d];
      const float rg = 1.f/(1.f+__expf(-(ir+hr)));
      const float zg = 1.f/(1.f+__expf(-(iz+hz)));
      const float ag = in_ + rg*hn;
      const float e2 = __expf(2.f*ag);
      const float ng = 1.f - 2.f/(e2+1.f);
      const float xp = sm.xpre[d];
      const float xq = (1.f-zg)*ng + zg*xp;
      sm.xpost[d] = xq;
      const size_t idx = (size_t)r0*TLEN*DDIM + (size_t)t*DDIM + d;
      if constexpr (FM==1) ((float*)Out)[idx] = xq;
      else ((__hip_bfloat16*)Out)[idx] = __float2bfloat16(xq);
    }
    __syncthreads();

    mv<FM,24,128,false>(Wemb, nullptr, DDIM, sm.xpost, kq, j0, [&](int j,float s){
      sm.e[j]=s+smb[OBEMB+j]; });

#pragma unroll 1
    for (int ib=0; ib<NBLK; ib++){
      const void* W1 = (const char*)eW1 + (size_t)ib*WB;
      const void* W2 = (const char*)eW2 + (size_t)ib*WB;
      const int bo = ib*NDIM;
      mv<FM,32,128,false>(W1, nullptr, NDIM, sm.e, kq, j0, [&](int j,float s){
        sm.h[j]=fmaxf(s+smb[OEB1+bo+j],0.f); });
      mv<FM,32,128,false>(W2, nullptr, NDIM, sm.h, kq, j0, [&](int j,float s){
        sm.e[j]+=s+smb[OEB2+bo+j]; });
    }
  }
}

__global__ __launch_bounds__(512, 4)
void linode_kernel(const void* Tp, const void* Xp, const void* Mp, const void* Ap,
                   const void* Wemb, const void* bemb, const void* Wproj, const void* bproj,
                   const void* eW1, const void* eb1, const void* eW2, const void* eb2,
                   const void* dW1, const void* db1, const void* dW2, const void* db2,
                   const void* Wih, const void* Whh, const void* bih, const void* bhh,
                   const u16* Ep, const int useE, void* Out)
{
  __shared__ SMState sm;
  __shared__ float smb[NBIAS];
  __shared__ __align__(16) u16 Ash[NDIM*A_STRIDE_E];
  __shared__ int s_f[4];
  const int tid = threadIdx.x;

  if (tid < 4) s_f[tid] = 0;
  __syncthreads();
  if (tid == 0){
    int all0 = 1;
    for (int k=0;k<8;k++) all0 &= (((const u32*)Ap)[129*k] == 0u);
    s_f[3] = all0;
  }
  {
    const u32* mw = (const u32*)Mp;
    int fb=0, ff=0, fg=0;
    for (int i=tid;i<2048;i+=512){
      const u32 w = mw[i];
      if (w == 0x3F803F80u) fb = 1;
      if ((w&0xFFFFu)==0x3F80u || (w>>16)==0x3F80u) ff = 1;
      if (w > 1u) fg = 1;
    }
    if (fb) atomicOr(&s_f[0],1);
    if (ff) atomicOr(&s_f[1],1);
    if (fg) atomicOr(&s_f[2],1);
  }
  __syncthreads();
  const int mode = s_f[0] ? 0 : (s_f[1] ? 1 : (s_f[2] ? 2 : 3));
  const int f32m = s_f[3];
  __syncthreads();

  if (!f32m && useE){
    stage_b<0>(eb1, smb+OEB1, NBLK*NDIM, tid);
    stage_b<0>(eb2, smb+OEB2, NBLK*NDIM, tid);
    stage_b<0>(db1, smb+ODB1, NBLK*NDIM, tid);
    stage_b<0>(db2, smb+ODB2, NBLK*NDIM, tid);
    stage_b<0>(bemb, smb+OBEMB, NDIM, tid);
    stage_b<0>(bproj, smb+OBPROJ, DDIM, tid);
    stage_b<0>(bih, smb+OBIH, 3*DDIM, tid);
    stage_b<0>(bhh, smb+OBHH, 3*DDIM, tid);
    __syncthreads();
    run_pipe(sm, smb, mode, Xp, Mp,
             (const u16*)Wemb, (const u16*)Wproj,
             (const u16*)eW1, (const u16*)eW2,
             (const u16*)dW1, (const u16*)dW2,
             (const u16*)Wih, (const u16*)Whh,
             Ep, (__hip_bfloat16*)Out);
  } else if (f32m){
    stage_b<1>(eb1, smb+OEB1, NBLK*NDIM, tid);
    stage_b<1>(eb2, smb+OEB2, NBLK*NDIM, tid);
    stage_b<1>(db1, smb+ODB1, NBLK*NDIM, tid);
    stage_b<1>(db2, smb+ODB2, NBLK*NDIM, tid);
    stage_b<1>(bemb, smb+OBEMB, NDIM, tid);
    stage_b<1>(bproj, smb+OBPROJ, DDIM, tid);
    stage_b<1>(bih, smb+OBIH, 3*DDIM, tid);
    stage_b<1>(bhh, smb+OBHH, 3*DDIM, tid);
    __syncthreads();
    run_all<1>(sm, smb, Ash, mode, Tp, Xp, Mp, Ap, Wemb, bemb, Wproj, bproj,
               eW1, eb1, eW2, eb2, dW1, db1, dW2, db2, Wih, Whh, bih, bhh, Out);
  } else {
    stage_b<0>(eb1, smb+OEB1, NBLK*NDIM, tid);
    stage_b<0>(eb2, smb+OEB2, NBLK*NDIM, tid);
    stage_b<0>(db1, smb+ODB1, NBLK*NDIM, tid);
    stage_b<0>(db2, smb+ODB2, NBLK*NDIM, tid);
    stage_b<0>(bemb, smb+OBEMB, NDIM, tid);
    stage_b<0>(bproj, smb+OBPROJ, DDIM, tid);
    stage_b<0>(bih, smb+OBIH, 3*DDIM, tid);
    stage_b<0>(bhh, smb+OBHH, 3*DDIM, tid);
    __syncthreads();
    run_all<0>(sm, smb, Ash, mode, Tp, Xp, Mp, Ap, Wemb, bemb, Wproj, bproj,
               eW1, eb1, eW2, eb2, dW1, db1, dW2, db2, Wih, Whh, bih, bhh, Out);
  }
}

extern "C" void kernel_launch(void* const* d_in, const int* in_sizes, int n_in,
                              void* d_out, int out_size, void* d_ws, size_t ws_size,
                              hipStream_t stream)
{
  (void)in_sizes; (void)n_in; (void)out_size;
  const int useE = (ws_size >= (size_t)TLEN*NDIM*NDIM*2) ? 1 : 0;
  if (useE)
    hipLaunchKernelGGL(expm_kernel, dim3(2*TLEN), dim3(256), 0, stream,
                       d_in[0], d_in[3], (u16*)d_ws);
  hipLaunchKernelGGL(linode_kernel, dim3(NBATCH), dim3(512), 0, stream,
                     d_in[0], d_in[1], d_in[2], d_in[3],
                     d_in[4], d_in[5], d_in[6], d_in[7],
                     d_in[8], d_in[9], d_in[10], d_in[11],
                     d_in[12], d_in[13], d_in[14], d_in[15],
                     d_in[16], d_in[17], d_in[18], d_in[19],
                     (const u16*)d_ws, useE, d_out);
}